// Round 4
// baseline (304.947 us; speedup 1.0000x reference)
//
#include <hip/hip_runtime.h>

#define NPTS 8192
#define NSLICE 16
#define SLICE_LEN (NPTS / NSLICE)
#define KNN 8

// Exact distance, replicating numpy rounding:
//   pj2 = ((x*x + y*y) + z*z); dot = fma-chain; d = (q2 + pj2) + (-2*dot)
// Used with IDENTICAL operation order in phases A, C, D -> bit-identical d.
__device__ __forceinline__ float dist_exact(float qx, float qy, float qz,
                                            float q2, float px, float py,
                                            float pz, float p2) {
  float dot = __fmaf_rn(qz, pz, __fmaf_rn(qy, py, __fmul_rn(qx, px)));
  float t1 = __fadd_rn(q2, p2);
  return __fadd_rn(t1, __fmul_rn(-2.0f, dot));
}

__device__ __forceinline__ float norm2_exact(float x, float y, float z) {
  return __fadd_rn(__fadd_rn(__fmul_rn(x, x), __fmul_rn(y, y)),
                   __fmul_rn(z, z));
}

// Value-only ascending top-8 bubble insert: 16 VOP2 (v_min/v_max) insts.
#define BUB_DECL                                                            \
  float d0 = 3.4e38f, d1 = 3.4e38f, d2 = 3.4e38f, d3 = 3.4e38f,            \
        d4 = 3.4e38f, d5 = 3.4e38f, d6 = 3.4e38f, d7 = 3.4e38f;
#define BUB1(s)                                                             \
  {                                                                         \
    float lo = fminf(carry, d##s);                                          \
    carry = fmaxf(carry, d##s);                                             \
    d##s = lo;                                                              \
  }
#define BUB_INSERT(dist)                                                    \
  {                                                                         \
    float carry = (dist);                                                   \
    BUB1(0) BUB1(1) BUB1(2) BUB1(3) BUB1(4) BUB1(5) BUB1(6) BUB1(7)         \
  }

// Lexicographic (d, idx) top-8 insert (cold path, phase D). Strict lex <
// keeps earlier-inserted equal keys in place; full (d,idx) key makes the
// result order-independent and identical to jax.lax.top_k tie rules.
#define TOPK_INSERT_LEX(dist, idx)                                          \
  {                                                                         \
    const float _d = (dist);                                                \
    const int _ix = (idx);                                                  \
    const bool c0 = _d < d0 || (_d == d0 && _ix < i0);                      \
    const bool c1 = _d < d1 || (_d == d1 && _ix < i1);                      \
    const bool c2 = _d < d2 || (_d == d2 && _ix < i2);                      \
    const bool c3 = _d < d3 || (_d == d3 && _ix < i3);                      \
    const bool c4 = _d < d4 || (_d == d4 && _ix < i4);                      \
    const bool c5 = _d < d5 || (_d == d5 && _ix < i5);                      \
    const bool c6 = _d < d6 || (_d == d6 && _ix < i6);                      \
    const bool c7 = _d < d7 || (_d == d7 && _ix < i7);                      \
    d7 = c7 ? (c6 ? d6 : _d) : d7; i7 = c7 ? (c6 ? i6 : _ix) : i7;          \
    d6 = c6 ? (c5 ? d5 : _d) : d6; i6 = c6 ? (c5 ? i5 : _ix) : i6;          \
    d5 = c5 ? (c4 ? d4 : _d) : d5; i5 = c5 ? (c4 ? i4 : _ix) : i5;          \
    d4 = c4 ? (c3 ? d3 : _d) : d4; i4 = c4 ? (c3 ? i3 : _ix) : i4;          \
    d3 = c3 ? (c2 ? d2 : _d) : d3; i3 = c3 ? (c2 ? i2 : _ix) : i3;          \
    d2 = c2 ? (c1 ? d1 : _d) : d2; i2 = c2 ? (c1 ? i1 : _ix) : i2;          \
    d1 = c1 ? (c0 ? d0 : _d) : d1; i1 = c1 ? (c0 ? i0 : _ix) : i1;          \
    d0 = c0 ? _d : d0;             i0 = c0 ? _ix : i0;                      \
  }

// ---------------------------------------------------------------------------
// Phase A: per (query, slice of 512) keep top-8 distance VALUES (no indices).
// ---------------------------------------------------------------------------
__global__ __launch_bounds__(256) void knn_vals_kernel(
    const float* __restrict__ pts, float* __restrict__ part_d) {
  __shared__ float4 sp[SLICE_LEN];
  const int t = threadIdx.x;
  const int q = blockIdx.x * 256 + t;
  const int jbase = blockIdx.y * SLICE_LEN;
  for (int p = t; p < SLICE_LEN; p += 256) {
    float x = pts[(jbase + p) * 3 + 0];
    float y = pts[(jbase + p) * 3 + 1];
    float z = pts[(jbase + p) * 3 + 2];
    sp[p] = make_float4(x, y, z, norm2_exact(x, y, z));
  }
  __syncthreads();
  const float qx = pts[q * 3 + 0], qy = pts[q * 3 + 1], qz = pts[q * 3 + 2];
  const float q2 = norm2_exact(qx, qy, qz);
  BUB_DECL;
#pragma unroll 4
  for (int p = 0; p < SLICE_LEN; ++p) {
    float4 pj = sp[p];
    float d = dist_exact(qx, qy, qz, q2, pj.x, pj.y, pj.z, pj.w);
    BUB_INSERT(d);
  }
  part_d[(blockIdx.y * KNN + 0) * NPTS + q] = d0;
  part_d[(blockIdx.y * KNN + 1) * NPTS + q] = d1;
  part_d[(blockIdx.y * KNN + 2) * NPTS + q] = d2;
  part_d[(blockIdx.y * KNN + 3) * NPTS + q] = d3;
  part_d[(blockIdx.y * KNN + 4) * NPTS + q] = d4;
  part_d[(blockIdx.y * KNN + 5) * NPTS + q] = d5;
  part_d[(blockIdx.y * KNN + 6) * NPTS + q] = d6;
  part_d[(blockIdx.y * KNN + 7) * NPTS + q] = d7;
}

// ---------------------------------------------------------------------------
// Phase B: merge 16 slices x 8 values per query -> tau = exact 8th-smallest.
// ---------------------------------------------------------------------------
__global__ __launch_bounds__(256) void knn_tau_kernel(
    const float* __restrict__ part_d, float* __restrict__ tau) {
  const int q = blockIdx.x * 256 + threadIdx.x;
  BUB_DECL;
  for (int sl = 0; sl < NSLICE; ++sl) {
#pragma unroll
    for (int e = 0; e < KNN; ++e) {
      float v = part_d[(sl * KNN + e) * NPTS + q];
      BUB_INSERT(v);
    }
  }
  tau[q] = d7;
}

// ---------------------------------------------------------------------------
// Phase C: rescan; survivors d <= tau -> compacted per-query list (cap 16).
// ---------------------------------------------------------------------------
__global__ __launch_bounds__(256) void knn_scan_kernel(
    const float* __restrict__ pts, const float* __restrict__ tau,
    int* __restrict__ cnt, int* __restrict__ surv) {
  __shared__ float4 sp[SLICE_LEN];
  const int t = threadIdx.x;
  const int q = blockIdx.x * 256 + t;
  const int jbase = blockIdx.y * SLICE_LEN;
  for (int p = t; p < SLICE_LEN; p += 256) {
    float x = pts[(jbase + p) * 3 + 0];
    float y = pts[(jbase + p) * 3 + 1];
    float z = pts[(jbase + p) * 3 + 2];
    sp[p] = make_float4(x, y, z, norm2_exact(x, y, z));
  }
  __syncthreads();
  const float qx = pts[q * 3 + 0], qy = pts[q * 3 + 1], qz = pts[q * 3 + 2];
  const float q2 = norm2_exact(qx, qy, qz);
  const float tq = tau[q];
#pragma unroll 4
  for (int p = 0; p < SLICE_LEN; ++p) {
    float4 pj = sp[p];
    float d = dist_exact(qx, qy, qz, q2, pj.x, pj.y, pj.z, pj.w);
    if (d <= tq) {
      int pos = atomicAdd(&cnt[q], 1);
      if (pos < 16) surv[q * 16 + pos] = jbase + p;
    }
  }
}

// ---------------------------------------------------------------------------
// Phase D: per query, exact lex (d, idx) top-8 over <=16 survivors -> nbr.
// ---------------------------------------------------------------------------
__global__ __launch_bounds__(256) void knn_select_kernel(
    const float* __restrict__ pts, const int* __restrict__ cnt,
    const int* __restrict__ surv, int* __restrict__ nbr) {
  const int q = blockIdx.x * 256 + threadIdx.x;
  const float qx = pts[q * 3 + 0], qy = pts[q * 3 + 1], qz = pts[q * 3 + 2];
  const float q2 = norm2_exact(qx, qy, qz);
  float d0 = 3.4e38f, d1 = 3.4e38f, d2 = 3.4e38f, d3 = 3.4e38f,
        d4 = 3.4e38f, d5 = 3.4e38f, d6 = 3.4e38f, d7 = 3.4e38f;
  int i0 = 0, i1 = 0, i2 = 0, i3 = 0, i4 = 0, i5 = 0, i6 = 0, i7 = 0;
  int m = cnt[q];
  if (m > 16) m = 16;
  for (int e = 0; e < m; ++e) {
    int j = surv[q * 16 + e];
    float px = pts[j * 3 + 0], py = pts[j * 3 + 1], pz = pts[j * 3 + 2];
    float d = dist_exact(qx, qy, qz, q2, px, py, pz, norm2_exact(px, py, pz));
    TOPK_INSERT_LEX(d, j);
  }
  nbr[q * KNN + 0] = i0;
  nbr[q * KNN + 1] = i1;
  nbr[q * KNN + 2] = i2;
  nbr[q * KNN + 3] = i3;
  nbr[q * KNN + 4] = i4;
  nbr[q * KNN + 5] = i5;
  nbr[q * KNN + 6] = i6;
  nbr[q * KNN + 7] = i7;
}

// ---------------------------------------------------------------------------
// Fused EdgeConv1: 64-edge x 64-ch H1 tile in LDS, GEMM with W2 (K=64),
// max over 8 edges/point, +b2, relu -> y (8192 x 128). grid dim3(2,1024).
// ---------------------------------------------------------------------------
__global__ __launch_bounds__(256) void gemm1_fused_kernel(
    const float* __restrict__ pts, const int* __restrict__ nbr,
    const float* __restrict__ W1, const float* __restrict__ b1,
    const float* __restrict__ W2, const float* __restrict__ b2,
    float* __restrict__ y) {
  __shared__ float es[64][6];
  __shared__ float W1s[6][64];
  __shared__ float b1s[64];
  __shared__ float As[64][64];  // As[k][edge]
  __shared__ float Bs[64][64];  // Bs[k][col]
  const int t = threadIdx.x;
  const int rowBase = blockIdx.y * 64;
  const int colBase = blockIdx.x * 64;

  for (int idx = t; idx < 384; idx += 256) W1s[idx >> 6][idx & 63] = W1[idx];
  if (t < 64) b1s[t] = b1[t];
  {
    int cq = t & 15, kr = t >> 4;
#pragma unroll
    for (int it = 0; it < 4; ++it) {
      int k = it * 16 + kr;
      *(float4*)&Bs[k][cq * 4] =
          *(const float4*)&W2[(size_t)k * 128 + colBase + cq * 4];
    }
  }
  if (t < 64) {
    int e = rowBase + t;
    int i = e >> 3;
    int j = nbr[e];
    float xi0 = pts[i * 3], xi1 = pts[i * 3 + 1], xi2 = pts[i * 3 + 2];
    es[t][0] = xi0;
    es[t][1] = xi1;
    es[t][2] = xi2;
    es[t][3] = pts[j * 3] - xi0;
    es[t][4] = pts[j * 3 + 1] - xi1;
    es[t][5] = pts[j * 3 + 2] - xi2;
  }
  __syncthreads();

  {
    const int e = t & 63, k0 = (t >> 6) * 16;
    const float f0 = es[e][0], f1 = es[e][1], f2 = es[e][2];
    const float f3 = es[e][3], f4 = es[e][4], f5 = es[e][5];
#pragma unroll
    for (int k = 0; k < 16; ++k) {
      int c = k0 + k;
      float v = b1s[c];
      v = fmaf(f0, W1s[0][c], v);
      v = fmaf(f1, W1s[1][c], v);
      v = fmaf(f2, W1s[2][c], v);
      v = fmaf(f3, W1s[3][c], v);
      v = fmaf(f4, W1s[4][c], v);
      v = fmaf(f5, W1s[5][c], v);
      As[c][e] = fmaxf(v, 0.0f);
    }
  }
  __syncthreads();

  const int tx = t & 15, ty = t >> 4;
  float acc[4][4] = {};
#pragma unroll 8
  for (int k = 0; k < 64; ++k) {
    float4 a = *(const float4*)&As[k][ty * 4];
    float4 b = *(const float4*)&Bs[k][tx * 4];
    const float ar[4] = {a.x, a.y, a.z, a.w};
    const float br[4] = {b.x, b.y, b.z, b.w};
#pragma unroll
    for (int i = 0; i < 4; ++i)
#pragma unroll
      for (int jj = 0; jj < 4; ++jj)
        acc[i][jj] = fmaf(ar[i], br[jj], acc[i][jj]);
  }
  __syncthreads();

  float* Mx = &As[0][0];
#pragma unroll
  for (int jj = 0; jj < 4; ++jj) {
    float m =
        fmaxf(fmaxf(acc[0][jj], acc[1][jj]), fmaxf(acc[2][jj], acc[3][jj]));
    Mx[ty * 64 + tx * 4 + jj] = m;
  }
  __syncthreads();
  if (t < 128) {
    int p = t >> 4, cq = t & 15;
    int c = cq * 4;
    float4 o;
    float* oa = (float*)&o;
#pragma unroll
    for (int jj = 0; jj < 4; ++jj) {
      float v = fmaxf(Mx[(2 * p) * 64 + c + jj], Mx[(2 * p + 1) * 64 + c + jj]);
      v += b2[colBase + c + jj];
      oa[jj] = fmaxf(v, 0.0f);
    }
    *(float4*)&y[(size_t)(blockIdx.y * 8 + p) * 128 + colBase + c] = o;
  }
}

// Build Wcat (128 x 256): cols 0..127 = W3[0:128,:], cols 128..255 = W3[128:256,:].
__global__ __launch_bounds__(256) void build_wcat_kernel(
    const float* __restrict__ W3, float* __restrict__ Wcat) {
  const int id = blockIdx.x * 256 + threadIdx.x;
  const int k = id >> 8, c = id & 255;
  Wcat[id] = (c < 128) ? W3[k * 128 + c] : W3[(128 + k) * 128 + (c - 128)];
}

// Per-edge first layer of EdgeConv2: H2[edge][c] = relu(A_i + C_j - C_i).
__global__ __launch_bounds__(256) void h2_edges_kernel(
    const float* __restrict__ AC, const int* __restrict__ nbr,
    float* __restrict__ H2) {
  const int id = blockIdx.x * 256 + threadIdx.x;
  const int te = id >> 5, cq = id & 31;
  const int i = te >> 3;
  const int j = nbr[te];
  const int c = cq * 4;
  float4 a = *(const float4*)&AC[(size_t)i * 256 + c];
  float4 ci = *(const float4*)&AC[(size_t)i * 256 + 128 + c];
  float4 cj = *(const float4*)&AC[(size_t)j * 256 + 128 + c];
  float4 h;
  h.x = fmaxf(a.x + cj.x - ci.x, 0.0f);
  h.y = fmaxf(a.y + cj.y - ci.y, 0.0f);
  h.z = fmaxf(a.z + cj.z - ci.z, 0.0f);
  h.w = fmaxf(a.w + cj.w - ci.w, 0.0f);
  *(float4*)&H2[(size_t)te * 128 + c] = h;
}

// ---------------------------------------------------------------------------
// Tiled fp32 GEMM: 64x64 tile, K-panel 64 LDS, 4x4 micro-tile.
// ---------------------------------------------------------------------------
template <bool SEGMAX, bool RELU>
__global__ __launch_bounds__(256) void gemm_kernel(
    const float* __restrict__ A, const float* __restrict__ B,
    const float* __restrict__ bias, int bias_limit, float* __restrict__ out,
    int K, int Nglob) {
  __shared__ float As[64][64];
  __shared__ float Bs[64][64];
  const int t = threadIdx.x;
  const int tx = t & 15, ty = t >> 4;
  const int rowBase = blockIdx.y * 64;
  const int colBase = blockIdx.x * 64;
  const float4* A4 = (const float4*)A;
  float acc[4][4] = {};

  for (int k0 = 0; k0 < K; k0 += 64) {
#pragma unroll
    for (int it = 0; it < 4; ++it) {
      int idx = it * 256 + t;
      int row = idx & 63, kq = idx >> 6;
      float4 av = A4[(size_t)(rowBase + row) * (K >> 2) + (k0 >> 2) + kq];
      As[kq * 4 + 0][row] = av.x;
      As[kq * 4 + 1][row] = av.y;
      As[kq * 4 + 2][row] = av.z;
      As[kq * 4 + 3][row] = av.w;
    }
#pragma unroll
    for (int it = 0; it < 4; ++it) {
      int idx = it * 256 + t;
      int cq = idx & 15, kr = idx >> 4;
      float4 bv = *(const float4*)&B[(size_t)(k0 + kr) * Nglob + colBase + cq * 4];
      *(float4*)&Bs[kr][cq * 4] = bv;
    }
    __syncthreads();
#pragma unroll 8
    for (int k = 0; k < 64; ++k) {
      float4 a = *(const float4*)&As[k][ty * 4];
      float4 b = *(const float4*)&Bs[k][tx * 4];
      const float ar[4] = {a.x, a.y, a.z, a.w};
      const float br[4] = {b.x, b.y, b.z, b.w};
#pragma unroll
      for (int i = 0; i < 4; ++i)
#pragma unroll
        for (int jj = 0; jj < 4; ++jj)
          acc[i][jj] = fmaf(ar[i], br[jj], acc[i][jj]);
    }
    __syncthreads();
  }

  if (SEGMAX) {
    float* Mx = &As[0][0];
#pragma unroll
    for (int jj = 0; jj < 4; ++jj) {
      float m = fmaxf(fmaxf(acc[0][jj], acc[1][jj]),
                      fmaxf(acc[2][jj], acc[3][jj]));
      Mx[ty * 64 + tx * 4 + jj] = m;
    }
    __syncthreads();
    if (t < 128) {
      int p = t >> 4, cq = t & 15;
      int c = cq * 4;
      float4 o;
      float* oa = (float*)&o;
#pragma unroll
      for (int jj = 0; jj < 4; ++jj) {
        float v = fmaxf(Mx[(2 * p) * 64 + c + jj], Mx[(2 * p + 1) * 64 + c + jj]);
        int cg = colBase + c + jj;
        if (cg < bias_limit) v += bias[cg];
        if (RELU) v = fmaxf(v, 0.0f);
        oa[jj] = v;
      }
      *(float4*)&out[(size_t)(blockIdx.y * 8 + p) * Nglob + colBase + c] = o;
    }
  } else {
#pragma unroll
    for (int i = 0; i < 4; ++i) {
      float4 o;
      float* oa = (float*)&o;
#pragma unroll
      for (int jj = 0; jj < 4; ++jj) {
        float v = acc[i][jj];
        int cg = colBase + tx * 4 + jj;
        if (cg < bias_limit) v += bias[cg];
        oa[jj] = v;
      }
      *(float4*)&out[(size_t)(rowBase + ty * 4 + i) * Nglob + colBase + tx * 4] = o;
    }
  }
}

extern "C" void kernel_launch(void* const* d_in, const int* in_sizes, int n_in,
                              void* d_out, int out_size, void* d_ws,
                              size_t ws_size, hipStream_t stream) {
  const float* pts = (const float*)d_in[0];
  const float* W1 = (const float*)d_in[1];
  const float* b1 = (const float*)d_in[2];
  const float* W2 = (const float*)d_in[3];
  const float* b2 = (const float*)d_in[4];
  const float* W3 = (const float*)d_in[5];
  const float* b3 = (const float*)d_in[6];
  const float* W4 = (const float*)d_in[7];
  const float* b4 = (const float*)d_in[8];
  float* out = (float*)d_out;

  float* w = (float*)d_ws;
  float* part_d = w;                    // 1048576 f
  float* tau = w + 1048576;             // 8192 f
  int* cnt = (int*)(w + 1056768);       // 8192 i
  int* surv = (int*)(w + 1064960);      // 131072 i
  int* nbr = (int*)(w + 1196032);       // 65536 i
  float* y = w + 1261568;               // 1048576 f
  float* Wcat = w + 2310144;            // 32768 f
  float* AC = w + 2342912;              // 2097152 f
  float* H2 = w + 4440064;              // 8388608 f  (total ~51.3 MB)

  // 1. KNN: values -> tau -> survivor scan -> exact select
  hipMemsetAsync(cnt, 0, NPTS * sizeof(int), stream);
  knn_vals_kernel<<<dim3(32, NSLICE), 256, 0, stream>>>(pts, part_d);
  knn_tau_kernel<<<32, 256, 0, stream>>>(part_d, tau);
  knn_scan_kernel<<<dim3(32, NSLICE), 256, 0, stream>>>(pts, tau, cnt, surv);
  knn_select_kernel<<<32, 256, 0, stream>>>(pts, cnt, surv, nbr);

  // 2. EdgeConv1 (fused H1 + GEMM + max8 + b2 + relu)
  gemm1_fused_kernel<<<dim3(2, 1024), 256, 0, stream>>>(pts, nbr, W1, b1, W2,
                                                        b2, y);

  // 3. EdgeConv2
  build_wcat_kernel<<<128, 256, 0, stream>>>(W3, Wcat);
  gemm_kernel<false, false><<<dim3(4, 128), 256, 0, stream>>>(
      y, Wcat, b3, 128, AC, 128, 256);
  h2_edges_kernel<<<8192, 256, 0, stream>>>(AC, nbr, H2);
  gemm_kernel<true, false><<<dim3(4, 1024), 256, 0, stream>>>(
      H2, W4, b4, 256, out, 128, 256);
}

// Round 5
// 303.425 us; speedup vs baseline: 1.0050x; 1.0050x over previous
//
#include <hip/hip_runtime.h>

#define NPTS 8192
#define NSLICE 16
#define SLICE_LEN (NPTS / NSLICE)
#define KNN 8

// Exact distance, replicating numpy rounding. IDENTICAL op order in all
// phases -> bit-identical d -> exact selection equivalence.
__device__ __forceinline__ float dist_exact(float qx, float qy, float qz,
                                            float q2, float px, float py,
                                            float pz, float p2) {
  float dot = __fmaf_rn(qz, pz, __fmaf_rn(qy, py, __fmul_rn(qx, px)));
  float t1 = __fadd_rn(q2, p2);
  return __fadd_rn(t1, __fmul_rn(-2.0f, dot));
}

__device__ __forceinline__ float norm2_exact(float x, float y, float z) {
  return __fadd_rn(__fadd_rn(__fmul_rn(x, x), __fmul_rn(y, y)),
                   __fmul_rn(z, z));
}

// Value-only ascending top-8 bubble insert: 16 VOP2 (v_min/v_max).
#define BUB_DECL                                                            \
  float d0 = 3.4e38f, d1 = 3.4e38f, d2 = 3.4e38f, d3 = 3.4e38f,            \
        d4 = 3.4e38f, d5 = 3.4e38f, d6 = 3.4e38f, d7 = 3.4e38f;
#define BUB1(s)                                                             \
  {                                                                         \
    float lo = fminf(carry, d##s);                                          \
    carry = fmaxf(carry, d##s);                                             \
    d##s = lo;                                                              \
  }
#define BUB_INSERT(dist)                                                    \
  {                                                                         \
    float carry = (dist);                                                   \
    BUB1(0) BUB1(1) BUB1(2) BUB1(3) BUB1(4) BUB1(5) BUB1(6) BUB1(7)         \
  }

// Lexicographic (d, idx) top-8 insert (cold path). Order-independent,
// identical to jax.lax.top_k tie rules.
#define TOPK_INSERT_LEX(dist, idx)                                          \
  {                                                                         \
    const float _d = (dist);                                                \
    const int _ix = (idx);                                                  \
    const bool c0 = _d < d0 || (_d == d0 && _ix < i0);                      \
    const bool c1 = _d < d1 || (_d == d1 && _ix < i1);                      \
    const bool c2 = _d < d2 || (_d == d2 && _ix < i2);                      \
    const bool c3 = _d < d3 || (_d == d3 && _ix < i3);                      \
    const bool c4 = _d < d4 || (_d == d4 && _ix < i4);                      \
    const bool c5 = _d < d5 || (_d == d5 && _ix < i5);                      \
    const bool c6 = _d < d6 || (_d == d6 && _ix < i6);                      \
    const bool c7 = _d < d7 || (_d == d7 && _ix < i7);                      \
    d7 = c7 ? (c6 ? d6 : _d) : d7; i7 = c7 ? (c6 ? i6 : _ix) : i7;          \
    d6 = c6 ? (c5 ? d5 : _d) : d6; i6 = c6 ? (c5 ? i5 : _ix) : i6;          \
    d5 = c5 ? (c4 ? d4 : _d) : d5; i5 = c5 ? (c4 ? i4 : _ix) : i5;          \
    d4 = c4 ? (c3 ? d3 : _d) : d4; i4 = c4 ? (c3 ? i3 : _ix) : i4;          \
    d3 = c3 ? (c2 ? d2 : _d) : d3; i3 = c3 ? (c2 ? i2 : _ix) : i3;          \
    d2 = c2 ? (c1 ? d1 : _d) : d2; i2 = c2 ? (c1 ? i1 : _ix) : i2;          \
    d1 = c1 ? (c0 ? d0 : _d) : d1; i1 = c1 ? (c0 ? i0 : _ix) : i1;          \
    d0 = c0 ? _d : d0;             i0 = c0 ? _ix : i0;                      \
  }

// ---------------------------------------------------------------------------
// Phase A: per (query, slice of 512) keep top-8 distance VALUES.
// ---------------------------------------------------------------------------
__global__ __launch_bounds__(256) void knn_vals_kernel(
    const float* __restrict__ pts, float* __restrict__ part_d) {
  __shared__ float4 sp[SLICE_LEN];
  const int t = threadIdx.x;
  const int q = blockIdx.x * 256 + t;
  const int jbase = blockIdx.y * SLICE_LEN;
  for (int p = t; p < SLICE_LEN; p += 256) {
    float x = pts[(jbase + p) * 3 + 0];
    float y = pts[(jbase + p) * 3 + 1];
    float z = pts[(jbase + p) * 3 + 2];
    sp[p] = make_float4(x, y, z, norm2_exact(x, y, z));
  }
  __syncthreads();
  const float qx = pts[q * 3 + 0], qy = pts[q * 3 + 1], qz = pts[q * 3 + 2];
  const float q2 = norm2_exact(qx, qy, qz);
  BUB_DECL;
#pragma unroll 4
  for (int p = 0; p < SLICE_LEN; ++p) {
    float4 pj = sp[p];
    float d = dist_exact(qx, qy, qz, q2, pj.x, pj.y, pj.z, pj.w);
    BUB_INSERT(d);
  }
  part_d[(blockIdx.y * KNN + 0) * NPTS + q] = d0;
  part_d[(blockIdx.y * KNN + 1) * NPTS + q] = d1;
  part_d[(blockIdx.y * KNN + 2) * NPTS + q] = d2;
  part_d[(blockIdx.y * KNN + 3) * NPTS + q] = d3;
  part_d[(blockIdx.y * KNN + 4) * NPTS + q] = d4;
  part_d[(blockIdx.y * KNN + 5) * NPTS + q] = d5;
  part_d[(blockIdx.y * KNN + 6) * NPTS + q] = d6;
  part_d[(blockIdx.y * KNN + 7) * NPTS + q] = d7;
}

// ---------------------------------------------------------------------------
// Phase B: merge 16 x 8 values -> tau = exact 8th-smallest distance.
// ---------------------------------------------------------------------------
__global__ __launch_bounds__(256) void knn_tau_kernel(
    const float* __restrict__ part_d, float* __restrict__ tau) {
  const int q = blockIdx.x * 256 + threadIdx.x;
  BUB_DECL;
  for (int sl = 0; sl < NSLICE; ++sl) {
#pragma unroll
    for (int e = 0; e < KNN; ++e) {
      float v = part_d[(sl * KNN + e) * NPTS + q];
      BUB_INSERT(v);
    }
  }
  tau[q] = d7;
}

// ---------------------------------------------------------------------------
// Phase C: rescan; survivors (d <= tau) -> 8 per-thread register slots,
// written unconditionally to surv[(slice*8+s)*NPTS+q] (-1 = empty).
// No atomics, no global counters.
// ---------------------------------------------------------------------------
__global__ __launch_bounds__(256) void knn_scan_kernel(
    const float* __restrict__ pts, const float* __restrict__ tau,
    int* __restrict__ surv) {
  __shared__ float4 sp[SLICE_LEN];
  const int t = threadIdx.x;
  const int q = blockIdx.x * 256 + t;
  const int jbase = blockIdx.y * SLICE_LEN;
  for (int p = t; p < SLICE_LEN; p += 256) {
    float x = pts[(jbase + p) * 3 + 0];
    float y = pts[(jbase + p) * 3 + 1];
    float z = pts[(jbase + p) * 3 + 2];
    sp[p] = make_float4(x, y, z, norm2_exact(x, y, z));
  }
  __syncthreads();
  const float qx = pts[q * 3 + 0], qy = pts[q * 3 + 1], qz = pts[q * 3 + 2];
  const float q2 = norm2_exact(qx, qy, qz);
  const float tq = tau[q];
  int n = 0;
  int s0 = -1, s1 = -1, s2 = -1, s3 = -1, s4 = -1, s5 = -1, s6 = -1, s7 = -1;
#pragma unroll 4
  for (int p = 0; p < SLICE_LEN; ++p) {
    float4 pj = sp[p];
    float d = dist_exact(qx, qy, qz, q2, pj.x, pj.y, pj.z, pj.w);
    if (d <= tq) {  // rare (expected ~0.56 hits per thread-slice)
      int j = jbase + p;
      s0 = (n == 0) ? j : s0;
      s1 = (n == 1) ? j : s1;
      s2 = (n == 2) ? j : s2;
      s3 = (n == 3) ? j : s3;
      s4 = (n == 4) ? j : s4;
      s5 = (n == 5) ? j : s5;
      s6 = (n == 6) ? j : s6;
      s7 = (n == 7) ? j : s7;
      ++n;
    }
  }
  const int base = blockIdx.y * KNN;
  surv[(base + 0) * NPTS + q] = s0;
  surv[(base + 1) * NPTS + q] = s1;
  surv[(base + 2) * NPTS + q] = s2;
  surv[(base + 3) * NPTS + q] = s3;
  surv[(base + 4) * NPTS + q] = s4;
  surv[(base + 5) * NPTS + q] = s5;
  surv[(base + 6) * NPTS + q] = s6;
  surv[(base + 7) * NPTS + q] = s7;
}

// ---------------------------------------------------------------------------
// Phase D: exact lex (d, idx) top-8 over the <=128 survivor slots -> nbr.
// ---------------------------------------------------------------------------
__global__ __launch_bounds__(256) void knn_select_kernel(
    const float* __restrict__ pts, const int* __restrict__ surv,
    int* __restrict__ nbr) {
  const int q = blockIdx.x * 256 + threadIdx.x;
  const float qx = pts[q * 3 + 0], qy = pts[q * 3 + 1], qz = pts[q * 3 + 2];
  const float q2 = norm2_exact(qx, qy, qz);
  float d0 = 3.4e38f, d1 = 3.4e38f, d2 = 3.4e38f, d3 = 3.4e38f,
        d4 = 3.4e38f, d5 = 3.4e38f, d6 = 3.4e38f, d7 = 3.4e38f;
  int i0 = 0, i1 = 0, i2 = 0, i3 = 0, i4 = 0, i5 = 0, i6 = 0, i7 = 0;
  for (int u = 0; u < NSLICE * KNN; ++u) {
    int j = surv[u * NPTS + q];
    if (j >= 0) {
      float px = pts[j * 3 + 0], py = pts[j * 3 + 1], pz = pts[j * 3 + 2];
      float d =
          dist_exact(qx, qy, qz, q2, px, py, pz, norm2_exact(px, py, pz));
      TOPK_INSERT_LEX(d, j);
    }
  }
  nbr[q * KNN + 0] = i0;
  nbr[q * KNN + 1] = i1;
  nbr[q * KNN + 2] = i2;
  nbr[q * KNN + 3] = i3;
  nbr[q * KNN + 4] = i4;
  nbr[q * KNN + 5] = i5;
  nbr[q * KNN + 6] = i6;
  nbr[q * KNN + 7] = i7;
}

// ---------------------------------------------------------------------------
// Fused EdgeConv1 (unchanged from R3): H1 tile in LDS, GEMM W2, max8,
// +b2, relu -> y (8192 x 128). grid dim3(2,1024).
// ---------------------------------------------------------------------------
__global__ __launch_bounds__(256) void gemm1_fused_kernel(
    const float* __restrict__ pts, const int* __restrict__ nbr,
    const float* __restrict__ W1, const float* __restrict__ b1,
    const float* __restrict__ W2, const float* __restrict__ b2,
    float* __restrict__ y) {
  __shared__ float es[64][6];
  __shared__ float W1s[6][64];
  __shared__ float b1s[64];
  __shared__ float As[64][64];
  __shared__ float Bs[64][64];
  const int t = threadIdx.x;
  const int rowBase = blockIdx.y * 64;
  const int colBase = blockIdx.x * 64;

  for (int idx = t; idx < 384; idx += 256) W1s[idx >> 6][idx & 63] = W1[idx];
  if (t < 64) b1s[t] = b1[t];
  {
    int cq = t & 15, kr = t >> 4;
#pragma unroll
    for (int it = 0; it < 4; ++it) {
      int k = it * 16 + kr;
      *(float4*)&Bs[k][cq * 4] =
          *(const float4*)&W2[(size_t)k * 128 + colBase + cq * 4];
    }
  }
  if (t < 64) {
    int e = rowBase + t;
    int i = e >> 3;
    int j = nbr[e];
    float xi0 = pts[i * 3], xi1 = pts[i * 3 + 1], xi2 = pts[i * 3 + 2];
    es[t][0] = xi0;
    es[t][1] = xi1;
    es[t][2] = xi2;
    es[t][3] = pts[j * 3] - xi0;
    es[t][4] = pts[j * 3 + 1] - xi1;
    es[t][5] = pts[j * 3 + 2] - xi2;
  }
  __syncthreads();

  {
    const int e = t & 63, k0 = (t >> 6) * 16;
    const float f0 = es[e][0], f1 = es[e][1], f2 = es[e][2];
    const float f3 = es[e][3], f4 = es[e][4], f5 = es[e][5];
#pragma unroll
    for (int k = 0; k < 16; ++k) {
      int c = k0 + k;
      float v = b1s[c];
      v = fmaf(f0, W1s[0][c], v);
      v = fmaf(f1, W1s[1][c], v);
      v = fmaf(f2, W1s[2][c], v);
      v = fmaf(f3, W1s[3][c], v);
      v = fmaf(f4, W1s[4][c], v);
      v = fmaf(f5, W1s[5][c], v);
      As[c][e] = fmaxf(v, 0.0f);
    }
  }
  __syncthreads();

  const int tx = t & 15, ty = t >> 4;
  float acc[4][4] = {};
#pragma unroll 8
  for (int k = 0; k < 64; ++k) {
    float4 a = *(const float4*)&As[k][ty * 4];
    float4 b = *(const float4*)&Bs[k][tx * 4];
    const float ar[4] = {a.x, a.y, a.z, a.w};
    const float br[4] = {b.x, b.y, b.z, b.w};
#pragma unroll
    for (int i = 0; i < 4; ++i)
#pragma unroll
      for (int jj = 0; jj < 4; ++jj)
        acc[i][jj] = fmaf(ar[i], br[jj], acc[i][jj]);
  }
  __syncthreads();

  float* Mx = &As[0][0];
#pragma unroll
  for (int jj = 0; jj < 4; ++jj) {
    float m =
        fmaxf(fmaxf(acc[0][jj], acc[1][jj]), fmaxf(acc[2][jj], acc[3][jj]));
    Mx[ty * 64 + tx * 4 + jj] = m;
  }
  __syncthreads();
  if (t < 128) {
    int p = t >> 4, cq = t & 15;
    int c = cq * 4;
    float4 o;
    float* oa = (float*)&o;
#pragma unroll
    for (int jj = 0; jj < 4; ++jj) {
      float v = fmaxf(Mx[(2 * p) * 64 + c + jj], Mx[(2 * p + 1) * 64 + c + jj]);
      v += b2[colBase + c + jj];
      oa[jj] = fmaxf(v, 0.0f);
    }
    *(float4*)&y[(size_t)(blockIdx.y * 8 + p) * 128 + colBase + c] = o;
  }
}

// Build Wcat (128 x 256) from W3 (256 x 128).
__global__ __launch_bounds__(256) void build_wcat_kernel(
    const float* __restrict__ W3, float* __restrict__ Wcat) {
  const int id = blockIdx.x * 256 + threadIdx.x;
  const int k = id >> 8, c = id & 255;
  Wcat[id] = (c < 128) ? W3[k * 128 + c] : W3[(128 + k) * 128 + (c - 128)];
}

// ---------------------------------------------------------------------------
// AC = y @ Wcat (+b3 on cols<128). Old 64x64 GEMM (small: 8192x128x256).
// ---------------------------------------------------------------------------
__global__ __launch_bounds__(256) void gemm_ac_kernel(
    const float* __restrict__ A, const float* __restrict__ B,
    const float* __restrict__ bias, float* __restrict__ out) {
  __shared__ float As[64][64];
  __shared__ float Bs[64][64];
  const int t = threadIdx.x;
  const int tx = t & 15, ty = t >> 4;
  const int rowBase = blockIdx.y * 64;
  const int colBase = blockIdx.x * 64;
  const float4* A4 = (const float4*)A;
  float acc[4][4] = {};
  const int K = 128, Nglob = 256;

  for (int k0 = 0; k0 < K; k0 += 64) {
#pragma unroll
    for (int it = 0; it < 4; ++it) {
      int idx = it * 256 + t;
      int row = idx & 63, kq = idx >> 6;
      float4 av = A4[(size_t)(rowBase + row) * (K >> 2) + (k0 >> 2) + kq];
      As[kq * 4 + 0][row] = av.x;
      As[kq * 4 + 1][row] = av.y;
      As[kq * 4 + 2][row] = av.z;
      As[kq * 4 + 3][row] = av.w;
    }
#pragma unroll
    for (int it = 0; it < 4; ++it) {
      int idx = it * 256 + t;
      int cq = idx & 15, kr = idx >> 4;
      float4 bv =
          *(const float4*)&B[(size_t)(k0 + kr) * Nglob + colBase + cq * 4];
      *(float4*)&Bs[kr][cq * 4] = bv;
    }
    __syncthreads();
#pragma unroll 8
    for (int k = 0; k < 64; ++k) {
      float4 a = *(const float4*)&As[k][ty * 4];
      float4 b = *(const float4*)&Bs[k][tx * 4];
      const float ar[4] = {a.x, a.y, a.z, a.w};
      const float br[4] = {b.x, b.y, b.z, b.w};
#pragma unroll
      for (int i = 0; i < 4; ++i)
#pragma unroll
        for (int jj = 0; jj < 4; ++jj)
          acc[i][jj] = fmaf(ar[i], br[jj], acc[i][jj]);
    }
    __syncthreads();
  }

#pragma unroll
  for (int i = 0; i < 4; ++i) {
    float4 o;
    float* oa = (float*)&o;
#pragma unroll
    for (int jj = 0; jj < 4; ++jj) {
      float v = acc[i][jj];
      int cg = colBase + tx * 4 + jj;
      if (cg < 128) v += bias[cg];
      oa[jj] = v;
    }
    *(float4*)&out[(size_t)(rowBase + ty * 4 + i) * Nglob + colBase + tx * 4] =
        o;
  }
}

// ---------------------------------------------------------------------------
// Fused EdgeConv2 second layer: A-panel H2 = relu(A_i + C_j - C_i) computed
// on the fly from AC (L2-resident), GEMM with W4 (K=128, panels of 32),
// 128x128 tile, 8x8 micro-tile, in-register segmax over each point's 8
// edges (thread's 8 rows == one point), +b4 -> out (8192 x 256).
// grid dim3(2, 512), 256 threads.
// ---------------------------------------------------------------------------
__global__ __launch_bounds__(256) void gemm2_fused_kernel(
    const float* __restrict__ AC, const int* __restrict__ nbr,
    const float* __restrict__ W4, const float* __restrict__ b4,
    float* __restrict__ out) {
  __shared__ float As[32][128];  // [k][edge]
  __shared__ float Bs[32][128];  // [k][col]
  const int t = threadIdx.x;
  const int tx = t & 15, ty = t >> 4;
  const int rowBase = blockIdx.y * 128;  // edges
  const int colBase = blockIdx.x * 128;
  const int e_loc = t >> 1, h = t & 1;  // 2 threads per edge
  const int edge = rowBase + e_loc;
  const int ip = edge >> 3;
  const int jp = nbr[edge];
  const float* ai_p = AC + (size_t)ip * 256;
  const float* ci_p = ai_p + 128;
  const float* cj_p = AC + (size_t)jp * 256 + 128;

  float acc[8][8] = {};

  for (int k0 = 0; k0 < 128; k0 += 32) {
    // ---- stage A: compute relu(a_i + c_j - c_i) for 16 k-values ----
    const int kb = k0 + h * 16;
    float4 A0 = *(const float4*)(ai_p + kb + 0);
    float4 A1 = *(const float4*)(ai_p + kb + 4);
    float4 A2 = *(const float4*)(ai_p + kb + 8);
    float4 A3 = *(const float4*)(ai_p + kb + 12);
    float4 C0 = *(const float4*)(ci_p + kb + 0);
    float4 C1 = *(const float4*)(ci_p + kb + 4);
    float4 C2 = *(const float4*)(ci_p + kb + 8);
    float4 C3 = *(const float4*)(ci_p + kb + 12);
    float4 D0 = *(const float4*)(cj_p + kb + 0);
    float4 D1 = *(const float4*)(cj_p + kb + 4);
    float4 D2 = *(const float4*)(cj_p + kb + 8);
    float4 D3 = *(const float4*)(cj_p + kb + 12);
    const int kw = h * 16;
    As[kw + 0][e_loc] = fmaxf(A0.x + D0.x - C0.x, 0.0f);
    As[kw + 1][e_loc] = fmaxf(A0.y + D0.y - C0.y, 0.0f);
    As[kw + 2][e_loc] = fmaxf(A0.z + D0.z - C0.z, 0.0f);
    As[kw + 3][e_loc] = fmaxf(A0.w + D0.w - C0.w, 0.0f);
    As[kw + 4][e_loc] = fmaxf(A1.x + D1.x - C1.x, 0.0f);
    As[kw + 5][e_loc] = fmaxf(A1.y + D1.y - C1.y, 0.0f);
    As[kw + 6][e_loc] = fmaxf(A1.z + D1.z - C1.z, 0.0f);
    As[kw + 7][e_loc] = fmaxf(A1.w + D1.w - C1.w, 0.0f);
    As[kw + 8][e_loc] = fmaxf(A2.x + D2.x - C2.x, 0.0f);
    As[kw + 9][e_loc] = fmaxf(A2.y + D2.y - C2.y, 0.0f);
    As[kw + 10][e_loc] = fmaxf(A2.z + D2.z - C2.z, 0.0f);
    As[kw + 11][e_loc] = fmaxf(A2.w + D2.w - C2.w, 0.0f);
    As[kw + 12][e_loc] = fmaxf(A3.x + D3.x - C3.x, 0.0f);
    As[kw + 13][e_loc] = fmaxf(A3.y + D3.y - C3.y, 0.0f);
    As[kw + 14][e_loc] = fmaxf(A3.z + D3.z - C3.z, 0.0f);
    As[kw + 15][e_loc] = fmaxf(A3.w + D3.w - C3.w, 0.0f);
    // ---- stage B: W4 panel ----
#pragma unroll
    for (int it = 0; it < 4; ++it) {
      int u = it * 256 + t;  // 0..1023 float4 units
      int kk = u >> 5, c4 = u & 31;
      *(float4*)&Bs[kk][c4 * 4] =
          *(const float4*)&W4[(size_t)(k0 + kk) * 256 + colBase + c4 * 4];
    }
    __syncthreads();
    // ---- micro-kernel: 8x8 per thread ----
#pragma unroll
    for (int kk = 0; kk < 32; ++kk) {
      float4 x0 = *(const float4*)&As[kk][ty * 8];
      float4 x1 = *(const float4*)&As[kk][ty * 8 + 4];
      float4 y0 = *(const float4*)&Bs[kk][tx * 8];
      float4 y1 = *(const float4*)&Bs[kk][tx * 8 + 4];
      const float ar[8] = {x0.x, x0.y, x0.z, x0.w, x1.x, x1.y, x1.z, x1.w};
      const float br[8] = {y0.x, y0.y, y0.z, y0.w, y1.x, y1.y, y1.z, y1.w};
#pragma unroll
      for (int r = 0; r < 8; ++r)
#pragma unroll
        for (int c = 0; c < 8; ++c)
          acc[r][c] = fmaf(ar[r], br[c], acc[r][c]);
    }
    __syncthreads();
  }

  // Epilogue: thread's 8 rows = edges of point (rowBase>>3)+ty exactly.
  const int point = (rowBase >> 3) + ty;
  float4 o0, o1;
  float* o0a = (float*)&o0;
  float* o1a = (float*)&o1;
#pragma unroll
  for (int c = 0; c < 8; ++c) {
    float m = acc[0][c];
#pragma unroll
    for (int r = 1; r < 8; ++r) m = fmaxf(m, acc[r][c]);
    float v = m + b4[colBase + tx * 8 + c];
    if (c < 4)
      o0a[c] = v;
    else
      o1a[c - 4] = v;
  }
  float* orow = &out[(size_t)point * 256 + colBase + tx * 8];
  *(float4*)orow = o0;
  *(float4*)(orow + 4) = o1;
}

extern "C" void kernel_launch(void* const* d_in, const int* in_sizes, int n_in,
                              void* d_out, int out_size, void* d_ws,
                              size_t ws_size, hipStream_t stream) {
  const float* pts = (const float*)d_in[0];
  const float* W1 = (const float*)d_in[1];
  const float* b1 = (const float*)d_in[2];
  const float* W2 = (const float*)d_in[3];
  const float* b2 = (const float*)d_in[4];
  const float* W3 = (const float*)d_in[5];
  const float* b3 = (const float*)d_in[6];
  const float* W4 = (const float*)d_in[7];
  const float* b4 = (const float*)d_in[8];
  float* out = (float*)d_out;

  float* w = (float*)d_ws;
  float* part_d = w;                    // 1048576 f
  float* tau = w + 1048576;             // 8192 f
  int* surv = (int*)(w + 1056768);      // 128*8192 = 1048576 i
  int* nbr = (int*)(w + 2105344);       // 65536 i
  float* y = w + 2170880;               // 1048576 f
  float* Wcat = w + 3219456;            // 32768 f
  float* AC = w + 3252224;              // 2097152 f  (total ~21.4 MB)

  // 1. KNN: values -> tau -> register-slot scan -> exact select
  knn_vals_kernel<<<dim3(32, NSLICE), 256, 0, stream>>>(pts, part_d);
  knn_tau_kernel<<<32, 256, 0, stream>>>(part_d, tau);
  knn_scan_kernel<<<dim3(32, NSLICE), 256, 0, stream>>>(pts, tau, surv);
  knn_select_kernel<<<32, 256, 0, stream>>>(pts, surv, nbr);

  // 2. EdgeConv1 (fused H1 + GEMM + max8 + b2 + relu)
  gemm1_fused_kernel<<<dim3(2, 1024), 256, 0, stream>>>(pts, nbr, W1, b1, W2,
                                                        b2, y);

  // 3. EdgeConv2: AC = y@Wcat (+b3), then fused H2+GEMM+max8+b4 -> out
  build_wcat_kernel<<<128, 256, 0, stream>>>(W3, Wcat);
  gemm_ac_kernel<<<dim3(4, 128), 256, 0, stream>>>(y, Wcat, b3, AC);
  gemm2_fused_kernel<<<dim3(2, 512), 256, 0, stream>>>(AC, nbr, W4, b4, out);
}

// Round 6
// 266.445 us; speedup vs baseline: 1.1445x; 1.1388x over previous
//
#include <hip/hip_runtime.h>

#define NPTS 8192
#define NSLICE 16
#define SLICE_LEN (NPTS / NSLICE)
#define KNN 8

// Exact distance, replicating numpy rounding. IDENTICAL op order in all
// phases -> bit-identical d -> exact selection equivalence.
__device__ __forceinline__ float dist_exact(float qx, float qy, float qz,
                                            float q2, float px, float py,
                                            float pz, float p2) {
  float dot = __fmaf_rn(qz, pz, __fmaf_rn(qy, py, __fmul_rn(qx, px)));
  float t1 = __fadd_rn(q2, p2);
  return __fadd_rn(t1, __fmul_rn(-2.0f, dot));
}

__device__ __forceinline__ float norm2_exact(float x, float y, float z) {
  return __fadd_rn(__fadd_rn(__fmul_rn(x, x), __fmul_rn(y, y)),
                   __fmul_rn(z, z));
}

// Value-only ascending top-8 bubble insert: 16 VOP2 (v_min/v_max).
#define BUB_DECL                                                            \
  float d0 = 3.4e38f, d1 = 3.4e38f, d2 = 3.4e38f, d3 = 3.4e38f,            \
        d4 = 3.4e38f, d5 = 3.4e38f, d6 = 3.4e38f, d7 = 3.4e38f;
#define BUB1(s)                                                             \
  {                                                                         \
    float lo = fminf(carry, d##s);                                          \
    carry = fmaxf(carry, d##s);                                             \
    d##s = lo;                                                              \
  }
#define BUB_INSERT(dist)                                                    \
  {                                                                         \
    float carry = (dist);                                                   \
    BUB1(0) BUB1(1) BUB1(2) BUB1(3) BUB1(4) BUB1(5) BUB1(6) BUB1(7)         \
  }

// Lexicographic (d, idx) top-8 insert (cold path). Order-independent,
// identical to jax.lax.top_k tie rules.
#define TOPK_INSERT_LEX(dist, idx)                                          \
  {                                                                         \
    const float _d = (dist);                                                \
    const int _ix = (idx);                                                  \
    const bool c0 = _d < d0 || (_d == d0 && _ix < i0);                      \
    const bool c1 = _d < d1 || (_d == d1 && _ix < i1);                      \
    const bool c2 = _d < d2 || (_d == d2 && _ix < i2);                      \
    const bool c3 = _d < d3 || (_d == d3 && _ix < i3);                      \
    const bool c4 = _d < d4 || (_d == d4 && _ix < i4);                      \
    const bool c5 = _d < d5 || (_d == d5 && _ix < i5);                      \
    const bool c6 = _d < d6 || (_d == d6 && _ix < i6);                      \
    const bool c7 = _d < d7 || (_d == d7 && _ix < i7);                      \
    d7 = c7 ? (c6 ? d6 : _d) : d7; i7 = c7 ? (c6 ? i6 : _ix) : i7;          \
    d6 = c6 ? (c5 ? d5 : _d) : d6; i6 = c6 ? (c5 ? i5 : _ix) : i6;          \
    d5 = c5 ? (c4 ? d4 : _d) : d5; i5 = c5 ? (c4 ? i4 : _ix) : i5;          \
    d4 = c4 ? (c3 ? d3 : _d) : d4; i4 = c4 ? (c3 ? i3 : _ix) : i4;          \
    d3 = c3 ? (c2 ? d2 : _d) : d3; i3 = c3 ? (c2 ? i2 : _ix) : i3;          \
    d2 = c2 ? (c1 ? d1 : _d) : d2; i2 = c2 ? (c1 ? i1 : _ix) : i2;          \
    d1 = c1 ? (c0 ? d0 : _d) : d1; i1 = c1 ? (c0 ? i0 : _ix) : i1;          \
    d0 = c0 ? _d : d0;             i0 = c0 ? _ix : i0;                      \
  }

// ---------------------------------------------------------------------------
// Phase A: per (query, slice of 512) keep top-8 distance VALUES.
// Output layout: part_d[q*128 + slice*8 + s] (per-query contiguous).
// ---------------------------------------------------------------------------
__global__ __launch_bounds__(256) void knn_vals_kernel(
    const float* __restrict__ pts, float* __restrict__ part_d) {
  __shared__ float4 sp[SLICE_LEN];
  const int t = threadIdx.x;
  const int q = blockIdx.x * 256 + t;
  const int jbase = blockIdx.y * SLICE_LEN;
  for (int p = t; p < SLICE_LEN; p += 256) {
    float x = pts[(jbase + p) * 3 + 0];
    float y = pts[(jbase + p) * 3 + 1];
    float z = pts[(jbase + p) * 3 + 2];
    sp[p] = make_float4(x, y, z, norm2_exact(x, y, z));
  }
  __syncthreads();
  const float qx = pts[q * 3 + 0], qy = pts[q * 3 + 1], qz = pts[q * 3 + 2];
  const float q2 = norm2_exact(qx, qy, qz);
  BUB_DECL;
#pragma unroll 4
  for (int p = 0; p < SLICE_LEN; ++p) {
    float4 pj = sp[p];
    float d = dist_exact(qx, qy, qz, q2, pj.x, pj.y, pj.z, pj.w);
    BUB_INSERT(d);
  }
  float* o = &part_d[(size_t)q * 128 + blockIdx.y * 8];
  o[0] = d0; o[1] = d1; o[2] = d2; o[3] = d3;
  o[4] = d4; o[5] = d5; o[6] = d6; o[7] = d7;
}

// ---------------------------------------------------------------------------
// Phase B: tau[q] = exact 8th-smallest over the 128 per-query values.
// Vectorized float4 loads from per-query-contiguous layout; high ILP.
// ---------------------------------------------------------------------------
__global__ __launch_bounds__(256) void knn_tau_kernel(
    const float* __restrict__ part_d, float* __restrict__ tau) {
  const int q = blockIdx.x * 256 + threadIdx.x;
  const float4* v4 = (const float4*)&part_d[(size_t)q * 128];
  BUB_DECL;
#pragma unroll 8
  for (int u = 0; u < 32; ++u) {
    float4 v = v4[u];
    BUB_INSERT(v.x);
    BUB_INSERT(v.y);
    BUB_INSERT(v.z);
    BUB_INSERT(v.w);
  }
  tau[q] = d7;
}

// ---------------------------------------------------------------------------
// Phase C: rescan; survivors (d <= tau) -> 8 per-thread register slot PAIRS
// (d and j), written unconditionally to survd/survj[q*128 + slice*8 + s]
// (j = -1 empty). No atomics. Capacity 8/slice is provably sufficient:
// at most 7 values are globally < tau, so any 9th+ per-slice hit has
// d == tau with >= 8 lower-index entries ahead of it -> rank > 8.
// ---------------------------------------------------------------------------
__global__ __launch_bounds__(256) void knn_scan_kernel(
    const float* __restrict__ pts, const float* __restrict__ tau,
    float* __restrict__ survd, int* __restrict__ survj) {
  __shared__ float4 sp[SLICE_LEN];
  const int t = threadIdx.x;
  const int q = blockIdx.x * 256 + t;
  const int jbase = blockIdx.y * SLICE_LEN;
  for (int p = t; p < SLICE_LEN; p += 256) {
    float x = pts[(jbase + p) * 3 + 0];
    float y = pts[(jbase + p) * 3 + 1];
    float z = pts[(jbase + p) * 3 + 2];
    sp[p] = make_float4(x, y, z, norm2_exact(x, y, z));
  }
  __syncthreads();
  const float qx = pts[q * 3 + 0], qy = pts[q * 3 + 1], qz = pts[q * 3 + 2];
  const float q2 = norm2_exact(qx, qy, qz);
  const float tq = tau[q];
  int n = 0;
  int s0 = -1, s1 = -1, s2 = -1, s3 = -1, s4 = -1, s5 = -1, s6 = -1, s7 = -1;
  float e0 = 0, e1 = 0, e2 = 0, e3 = 0, e4 = 0, e5 = 0, e6 = 0, e7 = 0;
#pragma unroll 4
  for (int p = 0; p < SLICE_LEN; ++p) {
    float4 pj = sp[p];
    float d = dist_exact(qx, qy, qz, q2, pj.x, pj.y, pj.z, pj.w);
    if (d <= tq) {  // rare (~0.56 hits per thread-slice)
      int j = jbase + p;
      s0 = (n == 0) ? j : s0; e0 = (n == 0) ? d : e0;
      s1 = (n == 1) ? j : s1; e1 = (n == 1) ? d : e1;
      s2 = (n == 2) ? j : s2; e2 = (n == 2) ? d : e2;
      s3 = (n == 3) ? j : s3; e3 = (n == 3) ? d : e3;
      s4 = (n == 4) ? j : s4; e4 = (n == 4) ? d : e4;
      s5 = (n == 5) ? j : s5; e5 = (n == 5) ? d : e5;
      s6 = (n == 6) ? j : s6; e6 = (n == 6) ? d : e6;
      s7 = (n == 7) ? j : s7; e7 = (n == 7) ? d : e7;
      ++n;
    }
  }
  const size_t base = (size_t)q * 128 + blockIdx.y * 8;
  survj[base + 0] = s0; survj[base + 1] = s1;
  survj[base + 2] = s2; survj[base + 3] = s3;
  survj[base + 4] = s4; survj[base + 5] = s5;
  survj[base + 6] = s6; survj[base + 7] = s7;
  survd[base + 0] = e0; survd[base + 1] = e1;
  survd[base + 2] = e2; survd[base + 3] = e3;
  survd[base + 4] = e4; survd[base + 5] = e5;
  survd[base + 6] = e6; survd[base + 7] = e7;
}

// ---------------------------------------------------------------------------
// Phase D: exact lex (d, idx) top-8 over the 128 (d,j) slots -> nbr.
// No pts gather, no distance recompute; pure vectorized streaming.
// ---------------------------------------------------------------------------
__global__ __launch_bounds__(256) void knn_select_kernel(
    const float* __restrict__ survd, const int* __restrict__ survj,
    int* __restrict__ nbr) {
  const int q = blockIdx.x * 256 + threadIdx.x;
  const float4* dv4 = (const float4*)&survd[(size_t)q * 128];
  const int4* jv4 = (const int4*)&survj[(size_t)q * 128];
  float d0 = 3.4e38f, d1 = 3.4e38f, d2 = 3.4e38f, d3 = 3.4e38f,
        d4 = 3.4e38f, d5 = 3.4e38f, d6 = 3.4e38f, d7 = 3.4e38f;
  int i0 = 0, i1 = 0, i2 = 0, i3 = 0, i4 = 0, i5 = 0, i6 = 0, i7 = 0;
#pragma unroll 8
  for (int u = 0; u < 32; ++u) {
    float4 dd = dv4[u];
    int4 jj = jv4[u];
    if (jj.x >= 0) TOPK_INSERT_LEX(dd.x, jj.x);
    if (jj.y >= 0) TOPK_INSERT_LEX(dd.y, jj.y);
    if (jj.z >= 0) TOPK_INSERT_LEX(dd.z, jj.z);
    if (jj.w >= 0) TOPK_INSERT_LEX(dd.w, jj.w);
  }
  nbr[q * KNN + 0] = i0;
  nbr[q * KNN + 1] = i1;
  nbr[q * KNN + 2] = i2;
  nbr[q * KNN + 3] = i3;
  nbr[q * KNN + 4] = i4;
  nbr[q * KNN + 5] = i5;
  nbr[q * KNN + 6] = i6;
  nbr[q * KNN + 7] = i7;
}

// ---------------------------------------------------------------------------
// Fused EdgeConv1: H1 tile in LDS, GEMM W2, max8, +b2, relu -> y (8192x128).
// grid dim3(2,1024).
// ---------------------------------------------------------------------------
__global__ __launch_bounds__(256) void gemm1_fused_kernel(
    const float* __restrict__ pts, const int* __restrict__ nbr,
    const float* __restrict__ W1, const float* __restrict__ b1,
    const float* __restrict__ W2, const float* __restrict__ b2,
    float* __restrict__ y) {
  __shared__ float es[64][6];
  __shared__ float W1s[6][64];
  __shared__ float b1s[64];
  __shared__ float As[64][64];
  __shared__ float Bs[64][64];
  const int t = threadIdx.x;
  const int rowBase = blockIdx.y * 64;
  const int colBase = blockIdx.x * 64;

  for (int idx = t; idx < 384; idx += 256) W1s[idx >> 6][idx & 63] = W1[idx];
  if (t < 64) b1s[t] = b1[t];
  {
    int cq = t & 15, kr = t >> 4;
#pragma unroll
    for (int it = 0; it < 4; ++it) {
      int k = it * 16 + kr;
      *(float4*)&Bs[k][cq * 4] =
          *(const float4*)&W2[(size_t)k * 128 + colBase + cq * 4];
    }
  }
  if (t < 64) {
    int e = rowBase + t;
    int i = e >> 3;
    int j = nbr[e];
    float xi0 = pts[i * 3], xi1 = pts[i * 3 + 1], xi2 = pts[i * 3 + 2];
    es[t][0] = xi0;
    es[t][1] = xi1;
    es[t][2] = xi2;
    es[t][3] = pts[j * 3] - xi0;
    es[t][4] = pts[j * 3 + 1] - xi1;
    es[t][5] = pts[j * 3 + 2] - xi2;
  }
  __syncthreads();

  {
    const int e = t & 63, k0 = (t >> 6) * 16;
    const float f0 = es[e][0], f1 = es[e][1], f2 = es[e][2];
    const float f3 = es[e][3], f4 = es[e][4], f5 = es[e][5];
#pragma unroll
    for (int k = 0; k < 16; ++k) {
      int c = k0 + k;
      float v = b1s[c];
      v = fmaf(f0, W1s[0][c], v);
      v = fmaf(f1, W1s[1][c], v);
      v = fmaf(f2, W1s[2][c], v);
      v = fmaf(f3, W1s[3][c], v);
      v = fmaf(f4, W1s[4][c], v);
      v = fmaf(f5, W1s[5][c], v);
      As[c][e] = fmaxf(v, 0.0f);
    }
  }
  __syncthreads();

  const int tx = t & 15, ty = t >> 4;
  float acc[4][4] = {};
#pragma unroll 8
  for (int k = 0; k < 64; ++k) {
    float4 a = *(const float4*)&As[k][ty * 4];
    float4 b = *(const float4*)&Bs[k][tx * 4];
    const float ar[4] = {a.x, a.y, a.z, a.w};
    const float br[4] = {b.x, b.y, b.z, b.w};
#pragma unroll
    for (int i = 0; i < 4; ++i)
#pragma unroll
      for (int jj = 0; jj < 4; ++jj)
        acc[i][jj] = fmaf(ar[i], br[jj], acc[i][jj]);
  }
  __syncthreads();

  float* Mx = &As[0][0];
#pragma unroll
  for (int jj = 0; jj < 4; ++jj) {
    float m =
        fmaxf(fmaxf(acc[0][jj], acc[1][jj]), fmaxf(acc[2][jj], acc[3][jj]));
    Mx[ty * 64 + tx * 4 + jj] = m;
  }
  __syncthreads();
  if (t < 128) {
    int p = t >> 4, cq = t & 15;
    int c = cq * 4;
    float4 o;
    float* oa = (float*)&o;
#pragma unroll
    for (int jj = 0; jj < 4; ++jj) {
      float v = fmaxf(Mx[(2 * p) * 64 + c + jj], Mx[(2 * p + 1) * 64 + c + jj]);
      v += b2[colBase + c + jj];
      oa[jj] = fmaxf(v, 0.0f);
    }
    *(float4*)&y[(size_t)(blockIdx.y * 8 + p) * 128 + colBase + c] = o;
  }
}

// Build Wcat (128 x 256) from W3 (256 x 128).
__global__ __launch_bounds__(256) void build_wcat_kernel(
    const float* __restrict__ W3, float* __restrict__ Wcat) {
  const int id = blockIdx.x * 256 + threadIdx.x;
  const int k = id >> 8, c = id & 255;
  Wcat[id] = (c < 128) ? W3[k * 128 + c] : W3[(128 + k) * 128 + (c - 128)];
}

// ---------------------------------------------------------------------------
// AC = y @ Wcat (+b3 on cols<128). 64x64 GEMM (8192x128x256).
// ---------------------------------------------------------------------------
__global__ __launch_bounds__(256) void gemm_ac_kernel(
    const float* __restrict__ A, const float* __restrict__ B,
    const float* __restrict__ bias, float* __restrict__ out) {
  __shared__ float As[64][64];
  __shared__ float Bs[64][64];
  const int t = threadIdx.x;
  const int tx = t & 15, ty = t >> 4;
  const int rowBase = blockIdx.y * 64;
  const int colBase = blockIdx.x * 64;
  const float4* A4 = (const float4*)A;
  float acc[4][4] = {};
  const int K = 128, Nglob = 256;

  for (int k0 = 0; k0 < K; k0 += 64) {
#pragma unroll
    for (int it = 0; it < 4; ++it) {
      int idx = it * 256 + t;
      int row = idx & 63, kq = idx >> 6;
      float4 av = A4[(size_t)(rowBase + row) * (K >> 2) + (k0 >> 2) + kq];
      As[kq * 4 + 0][row] = av.x;
      As[kq * 4 + 1][row] = av.y;
      As[kq * 4 + 2][row] = av.z;
      As[kq * 4 + 3][row] = av.w;
    }
#pragma unroll
    for (int it = 0; it < 4; ++it) {
      int idx = it * 256 + t;
      int cq = idx & 15, kr = idx >> 4;
      float4 bv =
          *(const float4*)&B[(size_t)(k0 + kr) * Nglob + colBase + cq * 4];
      *(float4*)&Bs[kr][cq * 4] = bv;
    }
    __syncthreads();
#pragma unroll 8
    for (int k = 0; k < 64; ++k) {
      float4 a = *(const float4*)&As[k][ty * 4];
      float4 b = *(const float4*)&Bs[k][tx * 4];
      const float ar[4] = {a.x, a.y, a.z, a.w};
      const float br[4] = {b.x, b.y, b.z, b.w};
#pragma unroll
      for (int i = 0; i < 4; ++i)
#pragma unroll
        for (int jj = 0; jj < 4; ++jj)
          acc[i][jj] = fmaf(ar[i], br[jj], acc[i][jj]);
    }
    __syncthreads();
  }

#pragma unroll
  for (int i = 0; i < 4; ++i) {
    float4 o;
    float* oa = (float*)&o;
#pragma unroll
    for (int jj = 0; jj < 4; ++jj) {
      float v = acc[i][jj];
      int cg = colBase + tx * 4 + jj;
      if (cg < 128) v += bias[cg];
      oa[jj] = v;
    }
    *(float4*)&out[(size_t)(rowBase + ty * 4 + i) * Nglob + colBase + tx * 4] =
        o;
  }
}

// ---------------------------------------------------------------------------
// Fused EdgeConv2 second layer: H2 = relu(A_i + C_j - C_i) on the fly from
// AC (L2-resident), GEMM W4 (K=128, panels 32), 128x128 tile, 8x8 micro,
// in-register segmax + b4 -> out. grid dim3(2, 512).
// ---------------------------------------------------------------------------
__global__ __launch_bounds__(256) void gemm2_fused_kernel(
    const float* __restrict__ AC, const int* __restrict__ nbr,
    const float* __restrict__ W4, const float* __restrict__ b4,
    float* __restrict__ out) {
  __shared__ float As[32][128];
  __shared__ float Bs[32][128];
  const int t = threadIdx.x;
  const int tx = t & 15, ty = t >> 4;
  const int rowBase = blockIdx.y * 128;
  const int colBase = blockIdx.x * 128;
  const int e_loc = t >> 1, h = t & 1;
  const int edge = rowBase + e_loc;
  const int ip = edge >> 3;
  const int jp = nbr[edge];
  const float* ai_p = AC + (size_t)ip * 256;
  const float* ci_p = ai_p + 128;
  const float* cj_p = AC + (size_t)jp * 256 + 128;

  float acc[8][8] = {};

  for (int k0 = 0; k0 < 128; k0 += 32) {
    const int kb = k0 + h * 16;
    float4 A0 = *(const float4*)(ai_p + kb + 0);
    float4 A1 = *(const float4*)(ai_p + kb + 4);
    float4 A2 = *(const float4*)(ai_p + kb + 8);
    float4 A3 = *(const float4*)(ai_p + kb + 12);
    float4 C0 = *(const float4*)(ci_p + kb + 0);
    float4 C1 = *(const float4*)(ci_p + kb + 4);
    float4 C2 = *(const float4*)(ci_p + kb + 8);
    float4 C3 = *(const float4*)(ci_p + kb + 12);
    float4 D0 = *(const float4*)(cj_p + kb + 0);
    float4 D1 = *(const float4*)(cj_p + kb + 4);
    float4 D2 = *(const float4*)(cj_p + kb + 8);
    float4 D3 = *(const float4*)(cj_p + kb + 12);
    const int kw = h * 16;
    As[kw + 0][e_loc] = fmaxf(A0.x + D0.x - C0.x, 0.0f);
    As[kw + 1][e_loc] = fmaxf(A0.y + D0.y - C0.y, 0.0f);
    As[kw + 2][e_loc] = fmaxf(A0.z + D0.z - C0.z, 0.0f);
    As[kw + 3][e_loc] = fmaxf(A0.w + D0.w - C0.w, 0.0f);
    As[kw + 4][e_loc] = fmaxf(A1.x + D1.x - C1.x, 0.0f);
    As[kw + 5][e_loc] = fmaxf(A1.y + D1.y - C1.y, 0.0f);
    As[kw + 6][e_loc] = fmaxf(A1.z + D1.z - C1.z, 0.0f);
    As[kw + 7][e_loc] = fmaxf(A1.w + D1.w - C1.w, 0.0f);
    As[kw + 8][e_loc] = fmaxf(A2.x + D2.x - C2.x, 0.0f);
    As[kw + 9][e_loc] = fmaxf(A2.y + D2.y - C2.y, 0.0f);
    As[kw + 10][e_loc] = fmaxf(A2.z + D2.z - C2.z, 0.0f);
    As[kw + 11][e_loc] = fmaxf(A2.w + D2.w - C2.w, 0.0f);
    As[kw + 12][e_loc] = fmaxf(A3.x + D3.x - C3.x, 0.0f);
    As[kw + 13][e_loc] = fmaxf(A3.y + D3.y - C3.y, 0.0f);
    As[kw + 14][e_loc] = fmaxf(A3.z + D3.z - C3.z, 0.0f);
    As[kw + 15][e_loc] = fmaxf(A3.w + D3.w - C3.w, 0.0f);
#pragma unroll
    for (int it = 0; it < 4; ++it) {
      int u = it * 256 + t;
      int kk = u >> 5, c4 = u & 31;
      *(float4*)&Bs[kk][c4 * 4] =
          *(const float4*)&W4[(size_t)(k0 + kk) * 256 + colBase + c4 * 4];
    }
    __syncthreads();
#pragma unroll
    for (int kk = 0; kk < 32; ++kk) {
      float4 x0 = *(const float4*)&As[kk][ty * 8];
      float4 x1 = *(const float4*)&As[kk][ty * 8 + 4];
      float4 y0 = *(const float4*)&Bs[kk][tx * 8];
      float4 y1 = *(const float4*)&Bs[kk][tx * 8 + 4];
      const float ar[8] = {x0.x, x0.y, x0.z, x0.w, x1.x, x1.y, x1.z, x1.w};
      const float br[8] = {y0.x, y0.y, y0.z, y0.w, y1.x, y1.y, y1.z, y1.w};
#pragma unroll
      for (int r = 0; r < 8; ++r)
#pragma unroll
        for (int c = 0; c < 8; ++c)
          acc[r][c] = fmaf(ar[r], br[c], acc[r][c]);
    }
    __syncthreads();
  }

  const int point = (rowBase >> 3) + ty;
  float4 o0, o1;
  float* o0a = (float*)&o0;
  float* o1a = (float*)&o1;
#pragma unroll
  for (int c = 0; c < 8; ++c) {
    float m = acc[0][c];
#pragma unroll
    for (int r = 1; r < 8; ++r) m = fmaxf(m, acc[r][c]);
    float v = m + b4[colBase + tx * 8 + c];
    if (c < 4)
      o0a[c] = v;
    else
      o1a[c - 4] = v;
  }
  float* orow = &out[(size_t)point * 256 + colBase + tx * 8];
  *(float4*)orow = o0;
  *(float4*)(orow + 4) = o1;
}

extern "C" void kernel_launch(void* const* d_in, const int* in_sizes, int n_in,
                              void* d_out, int out_size, void* d_ws,
                              size_t ws_size, hipStream_t stream) {
  const float* pts = (const float*)d_in[0];
  const float* W1 = (const float*)d_in[1];
  const float* b1 = (const float*)d_in[2];
  const float* W2 = (const float*)d_in[3];
  const float* b2 = (const float*)d_in[4];
  const float* W3 = (const float*)d_in[5];
  const float* b3 = (const float*)d_in[6];
  const float* W4 = (const float*)d_in[7];
  const float* b4 = (const float*)d_in[8];
  float* out = (float*)d_out;

  float* w = (float*)d_ws;
  float* part_d = w;                    // 1048576 f
  float* tau = w + 1048576;             // 8192 f
  float* survd = w + 1056768;           // 1048576 f
  int* survj = (int*)(w + 2105344);     // 1048576 i
  int* nbr = (int*)(w + 3153920);       // 65536 i
  float* y = w + 3219456;               // 1048576 f
  float* Wcat = w + 4268032;            // 32768 f
  float* AC = w + 4300800;              // 2097152 f  (~25.6 MB total)

  // 1. KNN: values -> tau -> (d,j) slot scan -> streaming exact select
  knn_vals_kernel<<<dim3(32, NSLICE), 256, 0, stream>>>(pts, part_d);
  knn_tau_kernel<<<32, 256, 0, stream>>>(part_d, tau);
  knn_scan_kernel<<<dim3(32, NSLICE), 256, 0, stream>>>(pts, tau, survd,
                                                        survj);
  knn_select_kernel<<<32, 256, 0, stream>>>(survd, survj, nbr);

  // 2. EdgeConv1 (fused H1 + GEMM + max8 + b2 + relu)
  gemm1_fused_kernel<<<dim3(2, 1024), 256, 0, stream>>>(pts, nbr, W1, b1, W2,
                                                        b2, y);

  // 3. EdgeConv2: AC = y@Wcat (+b3), then fused H2+GEMM+max8+b4 -> out
  build_wcat_kernel<<<128, 256, 0, stream>>>(W3, Wcat);
  gemm_ac_kernel<<<dim3(4, 128), 256, 0, stream>>>(y, Wcat, b3, AC);
  gemm2_fused_kernel<<<dim3(2, 512), 256, 0, stream>>>(AC, nbr, W4, b4, out);
}

// Round 7
// 249.732 us; speedup vs baseline: 1.2211x; 1.0669x over previous
//
#include <hip/hip_runtime.h>

#define NPTS 8192
#define NSLICE 16
#define SLICE_LEN (NPTS / NSLICE)
#define KNN 8

typedef short bf16x8 __attribute__((ext_vector_type(8)));
typedef float f32x4 __attribute__((ext_vector_type(4)));

// bf16 round-to-nearest-even split helpers.
__device__ __forceinline__ unsigned short f2bf(float x) {
  unsigned int u = __float_as_uint(x);
  return (unsigned short)((u + 0x7FFF + ((u >> 16) & 1)) >> 16);
}
__device__ __forceinline__ float bf2f(unsigned short s) {
  return __uint_as_float(((unsigned int)s) << 16);
}

// Exact distance, replicating numpy rounding. IDENTICAL op order in all
// phases -> bit-identical d -> exact selection equivalence.
__device__ __forceinline__ float dist_exact(float qx, float qy, float qz,
                                            float q2, float px, float py,
                                            float pz, float p2) {
  float dot = __fmaf_rn(qz, pz, __fmaf_rn(qy, py, __fmul_rn(qx, px)));
  float t1 = __fadd_rn(q2, p2);
  return __fadd_rn(t1, __fmul_rn(-2.0f, dot));
}

__device__ __forceinline__ float norm2_exact(float x, float y, float z) {
  return __fadd_rn(__fadd_rn(__fmul_rn(x, x), __fmul_rn(y, y)),
                   __fmul_rn(z, z));
}

// Value-only ascending top-8 bubble insert: 16 VOP2 (v_min/v_max).
#define BUB_DECL                                                            \
  float d0 = 3.4e38f, d1 = 3.4e38f, d2 = 3.4e38f, d3 = 3.4e38f,            \
        d4 = 3.4e38f, d5 = 3.4e38f, d6 = 3.4e38f, d7 = 3.4e38f;
#define BUB1(s)                                                             \
  {                                                                         \
    float lo = fminf(carry, d##s);                                          \
    carry = fmaxf(carry, d##s);                                             \
    d##s = lo;                                                              \
  }
#define BUB_INSERT(dist)                                                    \
  {                                                                         \
    float carry = (dist);                                                   \
    BUB1(0) BUB1(1) BUB1(2) BUB1(3) BUB1(4) BUB1(5) BUB1(6) BUB1(7)         \
  }

// Lexicographic (d, idx) top-8 insert (cold path). Order-independent,
// identical to jax.lax.top_k tie rules.
#define TOPK_INSERT_LEX(dist, idx)                                          \
  {                                                                         \
    const float _d = (dist);                                                \
    const int _ix = (idx);                                                  \
    const bool c0 = _d < d0 || (_d == d0 && _ix < i0);                      \
    const bool c1 = _d < d1 || (_d == d1 && _ix < i1);                      \
    const bool c2 = _d < d2 || (_d == d2 && _ix < i2);                      \
    const bool c3 = _d < d3 || (_d == d3 && _ix < i3);                      \
    const bool c4 = _d < d4 || (_d == d4 && _ix < i4);                      \
    const bool c5 = _d < d5 || (_d == d5 && _ix < i5);                      \
    const bool c6 = _d < d6 || (_d == d6 && _ix < i6);                      \
    const bool c7 = _d < d7 || (_d == d7 && _ix < i7);                      \
    d7 = c7 ? (c6 ? d6 : _d) : d7; i7 = c7 ? (c6 ? i6 : _ix) : i7;          \
    d6 = c6 ? (c5 ? d5 : _d) : d6; i6 = c6 ? (c5 ? i5 : _ix) : i6;          \
    d5 = c5 ? (c4 ? d4 : _d) : d5; i5 = c5 ? (c4 ? i4 : _ix) : i5;          \
    d4 = c4 ? (c3 ? d3 : _d) : d4; i4 = c4 ? (c3 ? i3 : _ix) : i4;          \
    d3 = c3 ? (c2 ? d2 : _d) : d3; i3 = c3 ? (c2 ? i2 : _ix) : i3;          \
    d2 = c2 ? (c1 ? d1 : _d) : d2; i2 = c2 ? (c1 ? i1 : _ix) : i2;          \
    d1 = c1 ? (c0 ? d0 : _d) : d1; i1 = c1 ? (c0 ? i0 : _ix) : i1;          \
    d0 = c0 ? _d : d0;             i0 = c0 ? _ix : i0;                      \
  }

// ---------------------------------------------------------------------------
// Phase A: per (query, slice of 512) keep top-8 distance VALUES.
// ---------------------------------------------------------------------------
__global__ __launch_bounds__(256) void knn_vals_kernel(
    const float* __restrict__ pts, float* __restrict__ part_d) {
  __shared__ float4 sp[SLICE_LEN];
  const int t = threadIdx.x;
  const int q = blockIdx.x * 256 + t;
  const int jbase = blockIdx.y * SLICE_LEN;
  for (int p = t; p < SLICE_LEN; p += 256) {
    float x = pts[(jbase + p) * 3 + 0];
    float y = pts[(jbase + p) * 3 + 1];
    float z = pts[(jbase + p) * 3 + 2];
    sp[p] = make_float4(x, y, z, norm2_exact(x, y, z));
  }
  __syncthreads();
  const float qx = pts[q * 3 + 0], qy = pts[q * 3 + 1], qz = pts[q * 3 + 2];
  const float q2 = norm2_exact(qx, qy, qz);
  BUB_DECL;
#pragma unroll 4
  for (int p = 0; p < SLICE_LEN; ++p) {
    float4 pj = sp[p];
    float d = dist_exact(qx, qy, qz, q2, pj.x, pj.y, pj.z, pj.w);
    BUB_INSERT(d);
  }
  float* o = &part_d[(size_t)q * 128 + blockIdx.y * 8];
  o[0] = d0; o[1] = d1; o[2] = d2; o[3] = d3;
  o[4] = d4; o[5] = d5; o[6] = d6; o[7] = d7;
}

// ---------------------------------------------------------------------------
// Phase B: tau[q] = exact 8th-smallest over the 128 per-query values.
// ---------------------------------------------------------------------------
__global__ __launch_bounds__(256) void knn_tau_kernel(
    const float* __restrict__ part_d, float* __restrict__ tau) {
  const int q = blockIdx.x * 256 + threadIdx.x;
  const float4* v4 = (const float4*)&part_d[(size_t)q * 128];
  BUB_DECL;
#pragma unroll 8
  for (int u = 0; u < 32; ++u) {
    float4 v = v4[u];
    BUB_INSERT(v.x);
    BUB_INSERT(v.y);
    BUB_INSERT(v.z);
    BUB_INSERT(v.w);
  }
  tau[q] = d7;
}

// ---------------------------------------------------------------------------
// Phase C: rescan; survivors (d <= tau) -> 8 per-thread (d,j) register
// slots, written unconditionally (j=-1 empty). No atomics.
// ---------------------------------------------------------------------------
__global__ __launch_bounds__(256) void knn_scan_kernel(
    const float* __restrict__ pts, const float* __restrict__ tau,
    float* __restrict__ survd, int* __restrict__ survj) {
  __shared__ float4 sp[SLICE_LEN];
  const int t = threadIdx.x;
  const int q = blockIdx.x * 256 + t;
  const int jbase = blockIdx.y * SLICE_LEN;
  for (int p = t; p < SLICE_LEN; p += 256) {
    float x = pts[(jbase + p) * 3 + 0];
    float y = pts[(jbase + p) * 3 + 1];
    float z = pts[(jbase + p) * 3 + 2];
    sp[p] = make_float4(x, y, z, norm2_exact(x, y, z));
  }
  __syncthreads();
  const float qx = pts[q * 3 + 0], qy = pts[q * 3 + 1], qz = pts[q * 3 + 2];
  const float q2 = norm2_exact(qx, qy, qz);
  const float tq = tau[q];
  int n = 0;
  int s0 = -1, s1 = -1, s2 = -1, s3 = -1, s4 = -1, s5 = -1, s6 = -1, s7 = -1;
  float e0 = 0, e1 = 0, e2 = 0, e3 = 0, e4 = 0, e5 = 0, e6 = 0, e7 = 0;
#pragma unroll 4
  for (int p = 0; p < SLICE_LEN; ++p) {
    float4 pj = sp[p];
    float d = dist_exact(qx, qy, qz, q2, pj.x, pj.y, pj.z, pj.w);
    if (d <= tq) {
      int j = jbase + p;
      s0 = (n == 0) ? j : s0; e0 = (n == 0) ? d : e0;
      s1 = (n == 1) ? j : s1; e1 = (n == 1) ? d : e1;
      s2 = (n == 2) ? j : s2; e2 = (n == 2) ? d : e2;
      s3 = (n == 3) ? j : s3; e3 = (n == 3) ? d : e3;
      s4 = (n == 4) ? j : s4; e4 = (n == 4) ? d : e4;
      s5 = (n == 5) ? j : s5; e5 = (n == 5) ? d : e5;
      s6 = (n == 6) ? j : s6; e6 = (n == 6) ? d : e6;
      s7 = (n == 7) ? j : s7; e7 = (n == 7) ? d : e7;
      ++n;
    }
  }
  const size_t base = (size_t)q * 128 + blockIdx.y * 8;
  survj[base + 0] = s0; survj[base + 1] = s1;
  survj[base + 2] = s2; survj[base + 3] = s3;
  survj[base + 4] = s4; survj[base + 5] = s5;
  survj[base + 6] = s6; survj[base + 7] = s7;
  survd[base + 0] = e0; survd[base + 1] = e1;
  survd[base + 2] = e2; survd[base + 3] = e3;
  survd[base + 4] = e4; survd[base + 5] = e5;
  survd[base + 6] = e6; survd[base + 7] = e7;
}

// ---------------------------------------------------------------------------
// Phase D: exact lex (d, idx) top-8 over the 128 (d,j) slots -> nbr.
// ---------------------------------------------------------------------------
__global__ __launch_bounds__(256) void knn_select_kernel(
    const float* __restrict__ survd, const int* __restrict__ survj,
    int* __restrict__ nbr) {
  const int q = blockIdx.x * 256 + threadIdx.x;
  const float4* dv4 = (const float4*)&survd[(size_t)q * 128];
  const int4* jv4 = (const int4*)&survj[(size_t)q * 128];
  float d0 = 3.4e38f, d1 = 3.4e38f, d2 = 3.4e38f, d3 = 3.4e38f,
        d4 = 3.4e38f, d5 = 3.4e38f, d6 = 3.4e38f, d7 = 3.4e38f;
  int i0 = 0, i1 = 0, i2 = 0, i3 = 0, i4 = 0, i5 = 0, i6 = 0, i7 = 0;
#pragma unroll 8
  for (int u = 0; u < 32; ++u) {
    float4 dd = dv4[u];
    int4 jj = jv4[u];
    if (jj.x >= 0) TOPK_INSERT_LEX(dd.x, jj.x);
    if (jj.y >= 0) TOPK_INSERT_LEX(dd.y, jj.y);
    if (jj.z >= 0) TOPK_INSERT_LEX(dd.z, jj.z);
    if (jj.w >= 0) TOPK_INSERT_LEX(dd.w, jj.w);
  }
  nbr[q * KNN + 0] = i0;
  nbr[q * KNN + 1] = i1;
  nbr[q * KNN + 2] = i2;
  nbr[q * KNN + 3] = i3;
  nbr[q * KNN + 4] = i4;
  nbr[q * KNN + 5] = i5;
  nbr[q * KNN + 6] = i6;
  nbr[q * KNN + 7] = i7;
}

// ---------------------------------------------------------------------------
// Fused EdgeConv1: H1 tile in LDS, GEMM W2, max8, +b2, relu -> y (8192x128).
// ---------------------------------------------------------------------------
__global__ __launch_bounds__(256) void gemm1_fused_kernel(
    const float* __restrict__ pts, const int* __restrict__ nbr,
    const float* __restrict__ W1, const float* __restrict__ b1,
    const float* __restrict__ W2, const float* __restrict__ b2,
    float* __restrict__ y) {
  __shared__ float es[64][6];
  __shared__ float W1s[6][64];
  __shared__ float b1s[64];
  __shared__ float As[64][64];
  __shared__ float Bs[64][64];
  const int t = threadIdx.x;
  const int rowBase = blockIdx.y * 64;
  const int colBase = blockIdx.x * 64;

  for (int idx = t; idx < 384; idx += 256) W1s[idx >> 6][idx & 63] = W1[idx];
  if (t < 64) b1s[t] = b1[t];
  {
    int cq = t & 15, kr = t >> 4;
#pragma unroll
    for (int it = 0; it < 4; ++it) {
      int k = it * 16 + kr;
      *(float4*)&Bs[k][cq * 4] =
          *(const float4*)&W2[(size_t)k * 128 + colBase + cq * 4];
    }
  }
  if (t < 64) {
    int e = rowBase + t;
    int i = e >> 3;
    int j = nbr[e];
    float xi0 = pts[i * 3], xi1 = pts[i * 3 + 1], xi2 = pts[i * 3 + 2];
    es[t][0] = xi0;
    es[t][1] = xi1;
    es[t][2] = xi2;
    es[t][3] = pts[j * 3] - xi0;
    es[t][4] = pts[j * 3 + 1] - xi1;
    es[t][5] = pts[j * 3 + 2] - xi2;
  }
  __syncthreads();

  {
    const int e = t & 63, k0 = (t >> 6) * 16;
    const float f0 = es[e][0], f1 = es[e][1], f2 = es[e][2];
    const float f3 = es[e][3], f4 = es[e][4], f5 = es[e][5];
#pragma unroll
    for (int k = 0; k < 16; ++k) {
      int c = k0 + k;
      float v = b1s[c];
      v = fmaf(f0, W1s[0][c], v);
      v = fmaf(f1, W1s[1][c], v);
      v = fmaf(f2, W1s[2][c], v);
      v = fmaf(f3, W1s[3][c], v);
      v = fmaf(f4, W1s[4][c], v);
      v = fmaf(f5, W1s[5][c], v);
      As[c][e] = fmaxf(v, 0.0f);
    }
  }
  __syncthreads();

  const int tx = t & 15, ty = t >> 4;
  float acc[4][4] = {};
#pragma unroll 8
  for (int k = 0; k < 64; ++k) {
    float4 a = *(const float4*)&As[k][ty * 4];
    float4 b = *(const float4*)&Bs[k][tx * 4];
    const float ar[4] = {a.x, a.y, a.z, a.w};
    const float br[4] = {b.x, b.y, b.z, b.w};
#pragma unroll
    for (int i = 0; i < 4; ++i)
#pragma unroll
      for (int jj = 0; jj < 4; ++jj)
        acc[i][jj] = fmaf(ar[i], br[jj], acc[i][jj]);
  }
  __syncthreads();

  float* Mx = &As[0][0];
#pragma unroll
  for (int jj = 0; jj < 4; ++jj) {
    float m =
        fmaxf(fmaxf(acc[0][jj], acc[1][jj]), fmaxf(acc[2][jj], acc[3][jj]));
    Mx[ty * 64 + tx * 4 + jj] = m;
  }
  __syncthreads();
  if (t < 128) {
    int p = t >> 4, cq = t & 15;
    int c = cq * 4;
    float4 o;
    float* oa = (float*)&o;
#pragma unroll
    for (int jj = 0; jj < 4; ++jj) {
      float v = fmaxf(Mx[(2 * p) * 64 + c + jj], Mx[(2 * p + 1) * 64 + c + jj]);
      v += b2[colBase + c + jj];
      oa[jj] = fmaxf(v, 0.0f);
    }
    *(float4*)&y[(size_t)(blockIdx.y * 8 + p) * 128 + colBase + c] = o;
  }
}

// Build Wcat (128 x 256) from W3 (256 x 128).
__global__ __launch_bounds__(256) void build_wcat_kernel(
    const float* __restrict__ W3, float* __restrict__ Wcat) {
  const int id = blockIdx.x * 256 + threadIdx.x;
  const int k = id >> 8, c = id & 255;
  Wcat[id] = (c < 128) ? W3[k * 128 + c] : W3[(128 + k) * 128 + (c - 128)];
}

// Split W4 (128x256 fp32, row-major) into transposed bf16 hi/lo:
// W4ht/W4lt[col*128 + k]. 32768 threads.
__global__ __launch_bounds__(256) void w4split_kernel(
    const float* __restrict__ W4, unsigned short* __restrict__ W4ht,
    unsigned short* __restrict__ W4lt) {
  const int id = blockIdx.x * 256 + threadIdx.x;  // 32768
  const int k = id >> 8, c = id & 255;
  float v = W4[k * 256 + c];
  unsigned short hi = f2bf(v);
  unsigned short lo = f2bf(v - bf2f(hi));
  W4ht[c * 128 + k] = hi;
  W4lt[c * 128 + k] = lo;
}

// ---------------------------------------------------------------------------
// AC = y @ Wcat (+b3 on cols<128). 64x64 GEMM (8192x128x256).
// ---------------------------------------------------------------------------
__global__ __launch_bounds__(256) void gemm_ac_kernel(
    const float* __restrict__ A, const float* __restrict__ B,
    const float* __restrict__ bias, float* __restrict__ out) {
  __shared__ float As[64][64];
  __shared__ float Bs[64][64];
  const int t = threadIdx.x;
  const int tx = t & 15, ty = t >> 4;
  const int rowBase = blockIdx.y * 64;
  const int colBase = blockIdx.x * 64;
  const float4* A4 = (const float4*)A;
  float acc[4][4] = {};
  const int K = 128, Nglob = 256;

  for (int k0 = 0; k0 < K; k0 += 64) {
#pragma unroll
    for (int it = 0; it < 4; ++it) {
      int idx = it * 256 + t;
      int row = idx & 63, kq = idx >> 6;
      float4 av = A4[(size_t)(rowBase + row) * (K >> 2) + (k0 >> 2) + kq];
      As[kq * 4 + 0][row] = av.x;
      As[kq * 4 + 1][row] = av.y;
      As[kq * 4 + 2][row] = av.z;
      As[kq * 4 + 3][row] = av.w;
    }
#pragma unroll
    for (int it = 0; it < 4; ++it) {
      int idx = it * 256 + t;
      int cq = idx & 15, kr = idx >> 4;
      float4 bv =
          *(const float4*)&B[(size_t)(k0 + kr) * Nglob + colBase + cq * 4];
      *(float4*)&Bs[kr][cq * 4] = bv;
    }
    __syncthreads();
#pragma unroll 8
    for (int k = 0; k < 64; ++k) {
      float4 a = *(const float4*)&As[k][ty * 4];
      float4 b = *(const float4*)&Bs[k][tx * 4];
      const float ar[4] = {a.x, a.y, a.z, a.w};
      const float br[4] = {b.x, b.y, b.z, b.w};
#pragma unroll
      for (int i = 0; i < 4; ++i)
#pragma unroll
        for (int jj = 0; jj < 4; ++jj)
          acc[i][jj] = fmaf(ar[i], br[jj], acc[i][jj]);
    }
    __syncthreads();
  }

#pragma unroll
  for (int i = 0; i < 4; ++i) {
    float4 o;
    float* oa = (float*)&o;
#pragma unroll
    for (int jj = 0; jj < 4; ++jj) {
      float v = acc[i][jj];
      int cg = colBase + tx * 4 + jj;
      if (cg < 128) v += bias[cg];
      oa[jj] = v;
    }
    *(float4*)&out[(size_t)(rowBase + ty * 4 + i) * Nglob + colBase + tx * 4] =
        o;
  }
}

// ---------------------------------------------------------------------------
// MFMA EdgeConv2 second layer (split-bf16): H2 = relu(A_i + C_j - C_i)
// computed fp32 from AC, split hi/lo bf16 into LDS; W4 pre-split hi/lo
// (transposed [col][k]). D = Hh*Wh + Hh*Wl + Hl*Wh in fp32 MFMA acc
// (error ~2^-16 rel). Block tile 128 edges x 128 cols, K-panels of 32.
// 4 waves; wave w: edges [w*32, w*32+32) x all 128 cols.
// MFMA 16x16x32 bf16: A[m=lane&15][k=quad*8+j]; B[k=quad*8+j][n=lane&15];
// C/D: col=lane&15, row=quad*4+reg. In-register segmax: max over 4 regs +
// shfl_xor(16) merges quad pairs -> one point's 8 edges. grid dim3(2,512).
// LDS rows padded to 40 shorts (80 B = 5 bank-quads, coprime 8 -> <=2-way).
// ---------------------------------------------------------------------------
__global__ __launch_bounds__(256) void gemm2_mfma_kernel(
    const float* __restrict__ AC, const int* __restrict__ nbr,
    const unsigned short* __restrict__ W4ht,
    const unsigned short* __restrict__ W4lt, const float* __restrict__ b4,
    float* __restrict__ out) {
  __shared__ unsigned short H2h[128 * 40];
  __shared__ unsigned short H2l[128 * 40];
  __shared__ unsigned short Wth[128 * 40];
  __shared__ unsigned short Wtl[128 * 40];
  const int t = threadIdx.x;
  const int rowBase = blockIdx.y * 128;
  const int colBase = blockIdx.x * 128;
  // staging role: 2 threads per edge/col, 16 k each
  const int eloc = t >> 1, hh = t & 1;
  const int kb = hh * 16;
  const int edge = rowBase + eloc;
  const int ip = edge >> 3;
  const int jp = nbr[edge];
  const float* ai_p = AC + (size_t)ip * 256;
  const float* ci_p = ai_p + 128;
  const float* cj_p = AC + (size_t)jp * 256 + 128;
  // mfma role
  const int lane = t & 63;
  const int w = t >> 6;
  const int q = lane >> 4;
  const int nidx = lane & 15;

  f32x4 acc[2][8];
#pragma unroll
  for (int mt = 0; mt < 2; ++mt)
#pragma unroll
    for (int nt = 0; nt < 8; ++nt) acc[mt][nt] = (f32x4){0.f, 0.f, 0.f, 0.f};

  for (int p = 0; p < 4; ++p) {
    const int k0 = p * 32;
    // ---- stage H2 hi/lo (fp32 compute, bf16 split) ----
    {
      float h2[16];
      const float4* a4 = (const float4*)(ai_p + k0 + kb);
      const float4* c4 = (const float4*)(ci_p + k0 + kb);
      const float4* d4 = (const float4*)(cj_p + k0 + kb);
#pragma unroll
      for (int u = 0; u < 4; ++u) {
        float4 a = a4[u], c = c4[u], d = d4[u];
        h2[u * 4 + 0] = fmaxf(a.x + d.x - c.x, 0.f);
        h2[u * 4 + 1] = fmaxf(a.y + d.y - c.y, 0.f);
        h2[u * 4 + 2] = fmaxf(a.z + d.z - c.z, 0.f);
        h2[u * 4 + 3] = fmaxf(a.w + d.w - c.w, 0.f);
      }
      unsigned int hp[8], lp[8];
#pragma unroll
      for (int u = 0; u < 8; ++u) {
        unsigned short h0 = f2bf(h2[2 * u]), h1 = f2bf(h2[2 * u + 1]);
        hp[u] = (unsigned int)h0 | ((unsigned int)h1 << 16);
        unsigned short l0 = f2bf(h2[2 * u] - bf2f(h0));
        unsigned short l1 = f2bf(h2[2 * u + 1] - bf2f(h1));
        lp[u] = (unsigned int)l0 | ((unsigned int)l1 << 16);
      }
      *(uint4*)&H2h[eloc * 40 + kb] = make_uint4(hp[0], hp[1], hp[2], hp[3]);
      *(uint4*)&H2h[eloc * 40 + kb + 8] =
          make_uint4(hp[4], hp[5], hp[6], hp[7]);
      *(uint4*)&H2l[eloc * 40 + kb] = make_uint4(lp[0], lp[1], lp[2], lp[3]);
      *(uint4*)&H2l[eloc * 40 + kb + 8] =
          make_uint4(lp[4], lp[5], lp[6], lp[7]);
    }
    // ---- stage W4t hi/lo (already split in global) ----
    {
      const size_t src = (size_t)(colBase + eloc) * 128 + k0 + kb;
      *(uint4*)&Wth[eloc * 40 + kb] = *(const uint4*)&W4ht[src];
      *(uint4*)&Wth[eloc * 40 + kb + 8] = *(const uint4*)&W4ht[src + 8];
      *(uint4*)&Wtl[eloc * 40 + kb] = *(const uint4*)&W4lt[src];
      *(uint4*)&Wtl[eloc * 40 + kb + 8] = *(const uint4*)&W4lt[src + 8];
    }
    __syncthreads();
    // ---- fragments + MFMA ----
    bf16x8 ah[2], al[2];
#pragma unroll
    for (int mt = 0; mt < 2; ++mt) {
      int row = w * 32 + mt * 16 + nidx;
      ah[mt] = *(const bf16x8*)&H2h[row * 40 + q * 8];
      al[mt] = *(const bf16x8*)&H2l[row * 40 + q * 8];
    }
#pragma unroll
    for (int nt = 0; nt < 8; ++nt) {
      int col = nt * 16 + nidx;
      bf16x8 bh = *(const bf16x8*)&Wth[col * 40 + q * 8];
      bf16x8 bl = *(const bf16x8*)&Wtl[col * 40 + q * 8];
#pragma unroll
      for (int mt = 0; mt < 2; ++mt) {
        acc[mt][nt] = __builtin_amdgcn_mfma_f32_16x16x32_bf16(
            ah[mt], bh, acc[mt][nt], 0, 0, 0);
        acc[mt][nt] = __builtin_amdgcn_mfma_f32_16x16x32_bf16(
            ah[mt], bl, acc[mt][nt], 0, 0, 0);
        acc[mt][nt] = __builtin_amdgcn_mfma_f32_16x16x32_bf16(
            al[mt], bh, acc[mt][nt], 0, 0, 0);
      }
    }
    __syncthreads();
  }

  // ---- epilogue: in-register segmax over each point's 8 edges ----
#pragma unroll
  for (int mt = 0; mt < 2; ++mt) {
    const int ebase = rowBase + w * 32 + mt * 16;
    const int pt0 = ebase >> 3;
#pragma unroll
    for (int nt = 0; nt < 8; ++nt) {
      f32x4 a = acc[mt][nt];
      float m = fmaxf(fmaxf(a[0], a[1]), fmaxf(a[2], a[3]));
      float o = fmaxf(m, __shfl_xor(m, 16, 64));
      int cg = colBase + nt * 16 + nidx;
      if (q == 0) {
        out[(size_t)pt0 * 256 + cg] = o + b4[cg];
      } else if (q == 2) {
        out[(size_t)(pt0 + 1) * 256 + cg] = o + b4[cg];
      }
    }
  }
}

extern "C" void kernel_launch(void* const* d_in, const int* in_sizes, int n_in,
                              void* d_out, int out_size, void* d_ws,
                              size_t ws_size, hipStream_t stream) {
  const float* pts = (const float*)d_in[0];
  const float* W1 = (const float*)d_in[1];
  const float* b1 = (const float*)d_in[2];
  const float* W2 = (const float*)d_in[3];
  const float* b2 = (const float*)d_in[4];
  const float* W3 = (const float*)d_in[5];
  const float* b3 = (const float*)d_in[6];
  const float* W4 = (const float*)d_in[7];
  const float* b4 = (const float*)d_in[8];
  float* out = (float*)d_out;

  float* w = (float*)d_ws;
  float* part_d = w;                           // 1048576 f
  float* tau = w + 1048576;                    // 8192 f
  float* survd = w + 1056768;                  // 1048576 f
  int* survj = (int*)(w + 2105344);            // 1048576 i
  int* nbr = (int*)(w + 3153920);              // 65536 i
  float* y = w + 3219456;                      // 1048576 f
  float* Wcat = w + 4268032;                   // 32768 f
  float* AC = w + 4300800;                     // 2097152 f
  unsigned short* W4ht = (unsigned short*)(w + 6397952);  // 32768 us
  unsigned short* W4lt = (unsigned short*)(w + 6414336);  // 32768 us

  // 1. KNN: values -> tau -> (d,j) slot scan -> streaming exact select
  knn_vals_kernel<<<dim3(32, NSLICE), 256, 0, stream>>>(pts, part_d);
  knn_tau_kernel<<<32, 256, 0, stream>>>(part_d, tau);
  knn_scan_kernel<<<dim3(32, NSLICE), 256, 0, stream>>>(pts, tau, survd,
                                                        survj);
  knn_select_kernel<<<32, 256, 0, stream>>>(survd, survj, nbr);

  // 2. EdgeConv1 (fused H1 + GEMM + max8 + b2 + relu)
  gemm1_fused_kernel<<<dim3(2, 1024), 256, 0, stream>>>(pts, nbr, W1, b1, W2,
                                                        b2, y);

  // 3. EdgeConv2: AC = y@Wcat (+b3), then MFMA H2+GEMM+max8+b4 -> out
  build_wcat_kernel<<<128, 256, 0, stream>>>(W3, Wcat);
  w4split_kernel<<<128, 256, 0, stream>>>(W4, W4ht, W4lt);
  gemm_ac_kernel<<<dim3(4, 128), 256, 0, stream>>>(y, Wcat, b3, AC);
  gemm2_mfma_kernel<<<dim3(2, 512), 256, 0, stream>>>(AC, nbr, W4ht, W4lt, b4,
                                                      out);
}

// Round 8
// 200.099 us; speedup vs baseline: 1.5240x; 1.2480x over previous
//
#include <hip/hip_runtime.h>

#define NPTS 8192
#define NSLICE 16
#define SLICE_LEN (NPTS / NSLICE)
#define KNN 8

typedef short bf16x8 __attribute__((ext_vector_type(8)));
typedef float f32x4 __attribute__((ext_vector_type(4)));

// bf16 round-to-nearest-even split helpers.
__device__ __forceinline__ unsigned short f2bf(float x) {
  unsigned int u = __float_as_uint(x);
  return (unsigned short)((u + 0x7FFF + ((u >> 16) & 1)) >> 16);
}
__device__ __forceinline__ float bf2f(unsigned short s) {
  return __uint_as_float(((unsigned int)s) << 16);
}

// Exact distance, replicating numpy rounding. Same bits every use.
__device__ __forceinline__ float dist_exact(float qx, float qy, float qz,
                                            float q2, float px, float py,
                                            float pz, float p2) {
  float dot = __fmaf_rn(qz, pz, __fmaf_rn(qy, py, __fmul_rn(qx, px)));
  float t1 = __fadd_rn(q2, p2);
  return __fadd_rn(t1, __fmul_rn(-2.0f, dot));
}

__device__ __forceinline__ float norm2_exact(float x, float y, float z) {
  return __fadd_rn(__fadd_rn(__fmul_rn(x, x), __fmul_rn(y, y)),
                   __fmul_rn(z, z));
}

// Monotone (d, idx) -> f64 key. Total-order map on d's float bits, then
// pack 32 d-bits + 13 idx bits into the mantissa of a [1,2) normal double:
// lex (d_bits, idx) ordering == IEEE f64 ordering. All idx distinct -> no
// ties; ascending keys == jax.lax.top_k order (stable, lowest idx first).
__device__ __forceinline__ double pack_key(float d, int idx) {
  unsigned int ub = __float_as_uint(d);
  ub ^= (((unsigned int)((int)ub >> 31)) | 0x80000000u);
  unsigned int lo = (ub << 13) | (unsigned int)idx;
  unsigned int hi = 0x3ff00000u | (ub >> 19);
  return __hiloint2double((int)hi, (int)lo);
}

#define KEY_DECL                                                            \
  const double KINF = __longlong_as_double(0x7ff0000000000000LL);           \
  double k0 = KINF, k1 = KINF, k2 = KINF, k3 = KINF, k4 = KINF, k5 = KINF,  \
         k6 = KINF, k7 = KINF;
#define KB1(s)                                                              \
  {                                                                         \
    double mn = fmin(carry, k##s);                                          \
    carry = fmax(carry, k##s);                                              \
    k##s = mn;                                                              \
  }
#define KEY_INSERT(key)                                                     \
  {                                                                         \
    double carry = (key);                                                   \
    KB1(0) KB1(1) KB1(2) KB1(3) KB1(4) KB1(5) KB1(6) KB1(7)                 \
  }

// ---------------------------------------------------------------------------
// KNN phase 1: per (query, slice of 512) keep top-8 (d,idx) as f64 keys.
// 4-wide candidate prefetch keeps 4 ds_read_b128 in flight per thread.
// Output: part_k[q*128 + slice*8 + s] (per-query contiguous, ascending).
// ---------------------------------------------------------------------------
__global__ __launch_bounds__(256) void knn_pairs_kernel(
    const float* __restrict__ pts, double* __restrict__ part_k) {
  __shared__ float4 sp[SLICE_LEN];
  const int t = threadIdx.x;
  const int q = blockIdx.x * 256 + t;
  const int jbase = blockIdx.y * SLICE_LEN;
  for (int p = t; p < SLICE_LEN; p += 256) {
    float x = pts[(jbase + p) * 3 + 0];
    float y = pts[(jbase + p) * 3 + 1];
    float z = pts[(jbase + p) * 3 + 2];
    sp[p] = make_float4(x, y, z, norm2_exact(x, y, z));
  }
  __syncthreads();
  const float qx = pts[q * 3 + 0], qy = pts[q * 3 + 1], qz = pts[q * 3 + 2];
  const float q2 = norm2_exact(qx, qy, qz);
  KEY_DECL;
  for (int p = 0; p < SLICE_LEN; p += 4) {
    float4 c0 = sp[p + 0];
    float4 c1 = sp[p + 1];
    float4 c2 = sp[p + 2];
    float4 c3 = sp[p + 3];
    {
      float d = dist_exact(qx, qy, qz, q2, c0.x, c0.y, c0.z, c0.w);
      KEY_INSERT(pack_key(d, jbase + p + 0));
    }
    {
      float d = dist_exact(qx, qy, qz, q2, c1.x, c1.y, c1.z, c1.w);
      KEY_INSERT(pack_key(d, jbase + p + 1));
    }
    {
      float d = dist_exact(qx, qy, qz, q2, c2.x, c2.y, c2.z, c2.w);
      KEY_INSERT(pack_key(d, jbase + p + 2));
    }
    {
      float d = dist_exact(qx, qy, qz, q2, c3.x, c3.y, c3.z, c3.w);
      KEY_INSERT(pack_key(d, jbase + p + 3));
    }
  }
  double* o = &part_k[(size_t)q * 128 + blockIdx.y * 8];
  o[0] = k0; o[1] = k1; o[2] = k2; o[3] = k3;
  o[4] = k4; o[5] = k5; o[6] = k6; o[7] = k7;
}

// ---------------------------------------------------------------------------
// KNN phase 2: merge 128 keys/query -> nbr (idx = low 13 bits of key).
// ---------------------------------------------------------------------------
__global__ __launch_bounds__(256) void knn_merge2_kernel(
    const double* __restrict__ part_k, int* __restrict__ nbr) {
  const int q = blockIdx.x * 256 + threadIdx.x;
  const double* kv = &part_k[(size_t)q * 128];
  KEY_DECL;
#pragma unroll 8
  for (int u = 0; u < 128; u += 4) {
    double a = kv[u + 0];
    double b = kv[u + 1];
    double c = kv[u + 2];
    double d = kv[u + 3];
    KEY_INSERT(a);
    KEY_INSERT(b);
    KEY_INSERT(c);
    KEY_INSERT(d);
  }
  nbr[q * KNN + 0] = __double2loint(k0) & 0x1fff;
  nbr[q * KNN + 1] = __double2loint(k1) & 0x1fff;
  nbr[q * KNN + 2] = __double2loint(k2) & 0x1fff;
  nbr[q * KNN + 3] = __double2loint(k3) & 0x1fff;
  nbr[q * KNN + 4] = __double2loint(k4) & 0x1fff;
  nbr[q * KNN + 5] = __double2loint(k5) & 0x1fff;
  nbr[q * KNN + 6] = __double2loint(k6) & 0x1fff;
  nbr[q * KNN + 7] = __double2loint(k7) & 0x1fff;
}

// ---------------------------------------------------------------------------
// Fused EdgeConv1: H1 tile in LDS, GEMM W2, max8, +b2, relu -> y (8192x128).
// ---------------------------------------------------------------------------
__global__ __launch_bounds__(256) void gemm1_fused_kernel(
    const float* __restrict__ pts, const int* __restrict__ nbr,
    const float* __restrict__ W1, const float* __restrict__ b1,
    const float* __restrict__ W2, const float* __restrict__ b2,
    float* __restrict__ y) {
  __shared__ float es[64][6];
  __shared__ float W1s[6][64];
  __shared__ float b1s[64];
  __shared__ float As[64][64];
  __shared__ float Bs[64][64];
  const int t = threadIdx.x;
  const int rowBase = blockIdx.y * 64;
  const int colBase = blockIdx.x * 64;

  for (int idx = t; idx < 384; idx += 256) W1s[idx >> 6][idx & 63] = W1[idx];
  if (t < 64) b1s[t] = b1[t];
  {
    int cq = t & 15, kr = t >> 4;
#pragma unroll
    for (int it = 0; it < 4; ++it) {
      int k = it * 16 + kr;
      *(float4*)&Bs[k][cq * 4] =
          *(const float4*)&W2[(size_t)k * 128 + colBase + cq * 4];
    }
  }
  if (t < 64) {
    int e = rowBase + t;
    int i = e >> 3;
    int j = nbr[e];
    float xi0 = pts[i * 3], xi1 = pts[i * 3 + 1], xi2 = pts[i * 3 + 2];
    es[t][0] = xi0;
    es[t][1] = xi1;
    es[t][2] = xi2;
    es[t][3] = pts[j * 3] - xi0;
    es[t][4] = pts[j * 3 + 1] - xi1;
    es[t][5] = pts[j * 3 + 2] - xi2;
  }
  __syncthreads();

  {
    const int e = t & 63, k0 = (t >> 6) * 16;
    const float f0 = es[e][0], f1 = es[e][1], f2 = es[e][2];
    const float f3 = es[e][3], f4 = es[e][4], f5 = es[e][5];
#pragma unroll
    for (int k = 0; k < 16; ++k) {
      int c = k0 + k;
      float v = b1s[c];
      v = fmaf(f0, W1s[0][c], v);
      v = fmaf(f1, W1s[1][c], v);
      v = fmaf(f2, W1s[2][c], v);
      v = fmaf(f3, W1s[3][c], v);
      v = fmaf(f4, W1s[4][c], v);
      v = fmaf(f5, W1s[5][c], v);
      As[c][e] = fmaxf(v, 0.0f);
    }
  }
  __syncthreads();

  const int tx = t & 15, ty = t >> 4;
  float acc[4][4] = {};
#pragma unroll 8
  for (int k = 0; k < 64; ++k) {
    float4 a = *(const float4*)&As[k][ty * 4];
    float4 b = *(const float4*)&Bs[k][tx * 4];
    const float ar[4] = {a.x, a.y, a.z, a.w};
    const float br[4] = {b.x, b.y, b.z, b.w};
#pragma unroll
    for (int i = 0; i < 4; ++i)
#pragma unroll
      for (int jj = 0; jj < 4; ++jj)
        acc[i][jj] = fmaf(ar[i], br[jj], acc[i][jj]);
  }
  __syncthreads();

  float* Mx = &As[0][0];
#pragma unroll
  for (int jj = 0; jj < 4; ++jj) {
    float m =
        fmaxf(fmaxf(acc[0][jj], acc[1][jj]), fmaxf(acc[2][jj], acc[3][jj]));
    Mx[ty * 64 + tx * 4 + jj] = m;
  }
  __syncthreads();
  if (t < 128) {
    int p = t >> 4, cq = t & 15;
    int c = cq * 4;
    float4 o;
    float* oa = (float*)&o;
#pragma unroll
    for (int jj = 0; jj < 4; ++jj) {
      float v = fmaxf(Mx[(2 * p) * 64 + c + jj], Mx[(2 * p + 1) * 64 + c + jj]);
      v += b2[colBase + c + jj];
      oa[jj] = fmaxf(v, 0.0f);
    }
    *(float4*)&y[(size_t)(blockIdx.y * 8 + p) * 128 + colBase + c] = o;
  }
}

// Build Wcat (128 x 256) from W3 (256 x 128).
__global__ __launch_bounds__(256) void build_wcat_kernel(
    const float* __restrict__ W3, float* __restrict__ Wcat) {
  const int id = blockIdx.x * 256 + threadIdx.x;
  const int k = id >> 8, c = id & 255;
  Wcat[id] = (c < 128) ? W3[k * 128 + c] : W3[(128 + k) * 128 + (c - 128)];
}

// Split W4 (128x256 fp32) into transposed bf16 hi/lo: W4ht/W4lt[col*128+k].
__global__ __launch_bounds__(256) void w4split_kernel(
    const float* __restrict__ W4, unsigned short* __restrict__ W4ht,
    unsigned short* __restrict__ W4lt) {
  const int id = blockIdx.x * 256 + threadIdx.x;  // 32768
  const int k = id >> 8, c = id & 255;
  float v = W4[k * 256 + c];
  unsigned short hi = f2bf(v);
  unsigned short lo = f2bf(v - bf2f(hi));
  W4ht[c * 128 + k] = hi;
  W4lt[c * 128 + k] = lo;
}

// ---------------------------------------------------------------------------
// AC = y @ Wcat (+b3 on cols<128). 64x64 GEMM (8192x128x256).
// ---------------------------------------------------------------------------
__global__ __launch_bounds__(256) void gemm_ac_kernel(
    const float* __restrict__ A, const float* __restrict__ B,
    const float* __restrict__ bias, float* __restrict__ out) {
  __shared__ float As[64][64];
  __shared__ float Bs[64][64];
  const int t = threadIdx.x;
  const int tx = t & 15, ty = t >> 4;
  const int rowBase = blockIdx.y * 64;
  const int colBase = blockIdx.x * 64;
  const float4* A4 = (const float4*)A;
  float acc[4][4] = {};
  const int K = 128, Nglob = 256;

  for (int k0 = 0; k0 < K; k0 += 64) {
#pragma unroll
    for (int it = 0; it < 4; ++it) {
      int idx = it * 256 + t;
      int row = idx & 63, kq = idx >> 6;
      float4 av = A4[(size_t)(rowBase + row) * (K >> 2) + (k0 >> 2) + kq];
      As[kq * 4 + 0][row] = av.x;
      As[kq * 4 + 1][row] = av.y;
      As[kq * 4 + 2][row] = av.z;
      As[kq * 4 + 3][row] = av.w;
    }
#pragma unroll
    for (int it = 0; it < 4; ++it) {
      int idx = it * 256 + t;
      int cq = idx & 15, kr = idx >> 4;
      float4 bv =
          *(const float4*)&B[(size_t)(k0 + kr) * Nglob + colBase + cq * 4];
      *(float4*)&Bs[kr][cq * 4] = bv;
    }
    __syncthreads();
#pragma unroll 8
    for (int k = 0; k < 64; ++k) {
      float4 a = *(const float4*)&As[k][ty * 4];
      float4 b = *(const float4*)&Bs[k][tx * 4];
      const float ar[4] = {a.x, a.y, a.z, a.w};
      const float br[4] = {b.x, b.y, b.z, b.w};
#pragma unroll
      for (int i = 0; i < 4; ++i)
#pragma unroll
        for (int jj = 0; jj < 4; ++jj)
          acc[i][jj] = fmaf(ar[i], br[jj], acc[i][jj]);
    }
    __syncthreads();
  }

#pragma unroll
  for (int i = 0; i < 4; ++i) {
    float4 o;
    float* oa = (float*)&o;
#pragma unroll
    for (int jj = 0; jj < 4; ++jj) {
      float v = acc[i][jj];
      int cg = colBase + tx * 4 + jj;
      if (cg < 128) v += bias[cg];
      oa[jj] = v;
    }
    *(float4*)&out[(size_t)(rowBase + ty * 4 + i) * Nglob + colBase + tx * 4] =
        o;
  }
}

// ---------------------------------------------------------------------------
// MFMA EdgeConv2 second layer (split-bf16), as R7 (verified):
// D = Hh*Wh + Hh*Wl + Hl*Wh in fp32 MFMA acc; in-register segmax + b4.
// ---------------------------------------------------------------------------
__global__ __launch_bounds__(256) void gemm2_mfma_kernel(
    const float* __restrict__ AC, const int* __restrict__ nbr,
    const unsigned short* __restrict__ W4ht,
    const unsigned short* __restrict__ W4lt, const float* __restrict__ b4,
    float* __restrict__ out) {
  __shared__ unsigned short H2h[128 * 40];
  __shared__ unsigned short H2l[128 * 40];
  __shared__ unsigned short Wth[128 * 40];
  __shared__ unsigned short Wtl[128 * 40];
  const int t = threadIdx.x;
  const int rowBase = blockIdx.y * 128;
  const int colBase = blockIdx.x * 128;
  const int eloc = t >> 1, hh = t & 1;
  const int kb = hh * 16;
  const int edge = rowBase + eloc;
  const int ip = edge >> 3;
  const int jp = nbr[edge];
  const float* ai_p = AC + (size_t)ip * 256;
  const float* ci_p = ai_p + 128;
  const float* cj_p = AC + (size_t)jp * 256 + 128;
  const int lane = t & 63;
  const int w = t >> 6;
  const int q = lane >> 4;
  const int nidx = lane & 15;

  f32x4 acc[2][8];
#pragma unroll
  for (int mt = 0; mt < 2; ++mt)
#pragma unroll
    for (int nt = 0; nt < 8; ++nt) acc[mt][nt] = (f32x4){0.f, 0.f, 0.f, 0.f};

  for (int p = 0; p < 4; ++p) {
    const int k0 = p * 32;
    {
      float h2[16];
      const float4* a4 = (const float4*)(ai_p + k0 + kb);
      const float4* c4 = (const float4*)(ci_p + k0 + kb);
      const float4* d4 = (const float4*)(cj_p + k0 + kb);
#pragma unroll
      for (int u = 0; u < 4; ++u) {
        float4 a = a4[u], c = c4[u], d = d4[u];
        h2[u * 4 + 0] = fmaxf(a.x + d.x - c.x, 0.f);
        h2[u * 4 + 1] = fmaxf(a.y + d.y - c.y, 0.f);
        h2[u * 4 + 2] = fmaxf(a.z + d.z - c.z, 0.f);
        h2[u * 4 + 3] = fmaxf(a.w + d.w - c.w, 0.f);
      }
      unsigned int hp[8], lp[8];
#pragma unroll
      for (int u = 0; u < 8; ++u) {
        unsigned short h0 = f2bf(h2[2 * u]), h1 = f2bf(h2[2 * u + 1]);
        hp[u] = (unsigned int)h0 | ((unsigned int)h1 << 16);
        unsigned short l0 = f2bf(h2[2 * u] - bf2f(h0));
        unsigned short l1 = f2bf(h2[2 * u + 1] - bf2f(h1));
        lp[u] = (unsigned int)l0 | ((unsigned int)l1 << 16);
      }
      *(uint4*)&H2h[eloc * 40 + kb] = make_uint4(hp[0], hp[1], hp[2], hp[3]);
      *(uint4*)&H2h[eloc * 40 + kb + 8] =
          make_uint4(hp[4], hp[5], hp[6], hp[7]);
      *(uint4*)&H2l[eloc * 40 + kb] = make_uint4(lp[0], lp[1], lp[2], lp[3]);
      *(uint4*)&H2l[eloc * 40 + kb + 8] =
          make_uint4(lp[4], lp[5], lp[6], lp[7]);
    }
    {
      const size_t src = (size_t)(colBase + eloc) * 128 + k0 + kb;
      *(uint4*)&Wth[eloc * 40 + kb] = *(const uint4*)&W4ht[src];
      *(uint4*)&Wth[eloc * 40 + kb + 8] = *(const uint4*)&W4ht[src + 8];
      *(uint4*)&Wtl[eloc * 40 + kb] = *(const uint4*)&W4lt[src];
      *(uint4*)&Wtl[eloc * 40 + kb + 8] = *(const uint4*)&W4lt[src + 8];
    }
    __syncthreads();
    bf16x8 ah[2], al[2];
#pragma unroll
    for (int mt = 0; mt < 2; ++mt) {
      int row = w * 32 + mt * 16 + nidx;
      ah[mt] = *(const bf16x8*)&H2h[row * 40 + q * 8];
      al[mt] = *(const bf16x8*)&H2l[row * 40 + q * 8];
    }
#pragma unroll
    for (int nt = 0; nt < 8; ++nt) {
      int col = nt * 16 + nidx;
      bf16x8 bh = *(const bf16x8*)&Wth[col * 40 + q * 8];
      bf16x8 bl = *(const bf16x8*)&Wtl[col * 40 + q * 8];
#pragma unroll
      for (int mt = 0; mt < 2; ++mt) {
        acc[mt][nt] = __builtin_amdgcn_mfma_f32_16x16x32_bf16(
            ah[mt], bh, acc[mt][nt], 0, 0, 0);
        acc[mt][nt] = __builtin_amdgcn_mfma_f32_16x16x32_bf16(
            ah[mt], bl, acc[mt][nt], 0, 0, 0);
        acc[mt][nt] = __builtin_amdgcn_mfma_f32_16x16x32_bf16(
            al[mt], bh, acc[mt][nt], 0, 0, 0);
      }
    }
    __syncthreads();
  }

#pragma unroll
  for (int mt = 0; mt < 2; ++mt) {
    const int ebase = rowBase + w * 32 + mt * 16;
    const int pt0 = ebase >> 3;
#pragma unroll
    for (int nt = 0; nt < 8; ++nt) {
      f32x4 a = acc[mt][nt];
      float m = fmaxf(fmaxf(a[0], a[1]), fmaxf(a[2], a[3]));
      float o = fmaxf(m, __shfl_xor(m, 16, 64));
      int cg = colBase + nt * 16 + nidx;
      if (q == 0) {
        out[(size_t)pt0 * 256 + cg] = o + b4[cg];
      } else if (q == 2) {
        out[(size_t)(pt0 + 1) * 256 + cg] = o + b4[cg];
      }
    }
  }
}

extern "C" void kernel_launch(void* const* d_in, const int* in_sizes, int n_in,
                              void* d_out, int out_size, void* d_ws,
                              size_t ws_size, hipStream_t stream) {
  const float* pts = (const float*)d_in[0];
  const float* W1 = (const float*)d_in[1];
  const float* b1 = (const float*)d_in[2];
  const float* W2 = (const float*)d_in[3];
  const float* b2 = (const float*)d_in[4];
  const float* W3 = (const float*)d_in[5];
  const float* b3 = (const float*)d_in[6];
  const float* W4 = (const float*)d_in[7];
  const float* b4 = (const float*)d_in[8];
  float* out = (float*)d_out;

  float* w = (float*)d_ws;
  double* part_k = (double*)w;                 // 8192*128 dbl = 2097152 f
  int* nbr = (int*)(w + 2097152);              // 65536 i
  float* y = w + 2162688;                      // 1048576 f
  float* Wcat = w + 3211264;                   // 32768 f
  float* AC = w + 3244032;                     // 2097152 f
  unsigned short* W4ht = (unsigned short*)(w + 5341184);  // 32768 us
  unsigned short* W4lt = (unsigned short*)(w + 5357568);  // 32768 us

  // 1. KNN: keyed (d,idx) f64 top-8 per slice -> merge -> nbr
  knn_pairs_kernel<<<dim3(32, NSLICE), 256, 0, stream>>>(pts, part_k);
  knn_merge2_kernel<<<32, 256, 0, stream>>>(part_k, nbr);

  // 2. EdgeConv1 (fused H1 + GEMM + max8 + b2 + relu)
  gemm1_fused_kernel<<<dim3(2, 1024), 256, 0, stream>>>(pts, nbr, W1, b1, W2,
                                                        b2, y);

  // 3. EdgeConv2: AC = y@Wcat (+b3), then MFMA H2+GEMM+max8+b4 -> out
  build_wcat_kernel<<<128, 256, 0, stream>>>(W3, Wcat);
  w4split_kernel<<<128, 256, 0, stream>>>(W4, W4ht, W4lt);
  gemm_ac_kernel<<<dim3(4, 128), 256, 0, stream>>>(y, Wcat, b3, AC);
  gemm2_mfma_kernel<<<dim3(2, 512), 256, 0, stream>>>(AC, nbr, W4ht, W4lt, b4,
                                                      out);
}